// Round 18
// baseline (1838.015 us; speedup 1.0000x reference)
//
#include <hip/hip_runtime.h>
#include <hip/hip_bf16.h>
#include <stdint.h>

// MoE head R18: gate reverted to R16 single-buffer (3 blocks/CU, 688us known
// -- R17's 2-buffer pipeline lost occupancy and regressed). Sparse expert:
// 4-buffer stage-ahead-3 pipeline (vmcnt(6)) to cover the scattered gathered-A
// latency (~900cyc > stage-ahead-2's ~600cyc cover), chunk-fastest grid.
// build_w1B moved AFTER gate/topk so panB is L3-hot for the sparse expert.
// Tiers: ws>=NEED1 sparse; >=NEED2 dense R10; else R1 fallback.

#define B_DIM  16384
#define H_DIM  4096
#define H2_DIM 2048
#define E_DIM  8

typedef __attribute__((ext_vector_type(8))) short short8;
typedef __attribute__((ext_vector_type(4))) float f32x4;

static __device__ __forceinline__ unsigned int bf16_rn(float f) {
    unsigned int u = __builtin_bit_cast(unsigned int, f);
    u += 0x7FFFu + ((u >> 16) & 1u);
    return u >> 16;
}
static __device__ __forceinline__ float bf16f(unsigned int h) {
    unsigned int u = h << 16;
    return __builtin_bit_cast(float, u);
}

static __device__ __forceinline__ void gload_lds16(const void* g, void* l) {
    __builtin_amdgcn_global_load_lds(
        (const __attribute__((address_space(1))) unsigned int*)g,
        (__attribute__((address_space(3))) unsigned int*)l,
        16, 0, 0);
}

// ---------------------------------------------------------------------------
// Prepass 1a: x fp32 -> panA (hi) only.  [tier-2]
// panA[bm256(64)][TT(128)]{16KB: [row(256)][slot(4)]{8 bf16}},
// stored slot = kslot ^ ((row>>1)&3).
// ---------------------------------------------------------------------------
__global__ __launch_bounds__(256) void build_xA_panels(
    const float* __restrict__ x, unsigned short* __restrict__ panA)
{
    const int t = blockIdx.x, bm = blockIdx.y, tid = threadIdx.x;
    const size_t ubase = (size_t)(bm * 64 + t) * 2 * 8192;
#pragma unroll
    for (int u = 0; u < 8; ++u) {
        const int gid = u * 256 + tid;
        const int h = gid >> 10, rem = gid & 1023;
        const int row = rem >> 2, slot = rem & 3;
        const int kslot = slot ^ ((row >> 1) & 3);
        const float* s = x + (size_t)(bm * 256 + row) * H_DIM
                           + t * 64 + h * 32 + kslot * 8;
        f32x4 a = ((const f32x4*)s)[0], b = ((const f32x4*)s)[1];
        uint4 o;
        o.x = bf16_rn(a[0]) | (bf16_rn(a[1]) << 16);
        o.y = bf16_rn(a[2]) | (bf16_rn(a[3]) << 16);
        o.z = bf16_rn(b[0]) | (bf16_rn(b[1]) << 16);
        o.w = bf16_rn(b[2]) | (bf16_rn(b[3]) << 16);
        *(uint4*)(panA + ubase + (size_t)h * 8192 + row * 32 + slot * 8) = o;
    }
}

// ---------------------------------------------------------------------------
// Prepass 1b: x fp32 -> panA (hi) + panAl (lo).  [tier-1]
// ---------------------------------------------------------------------------
__global__ __launch_bounds__(256) void build_xA_panels_hl(
    const float* __restrict__ x, unsigned short* __restrict__ panA,
    unsigned short* __restrict__ panAl)
{
    const int t = blockIdx.x, bm = blockIdx.y, tid = threadIdx.x;
    const size_t ubase = (size_t)(bm * 64 + t) * 2 * 8192;
#pragma unroll
    for (int u = 0; u < 8; ++u) {
        const int gid = u * 256 + tid;
        const int h = gid >> 10, rem = gid & 1023;
        const int row = rem >> 2, slot = rem & 3;
        const int kslot = slot ^ ((row >> 1) & 3);
        const float* s = x + (size_t)(bm * 256 + row) * H_DIM
                           + t * 64 + h * 32 + kslot * 8;
        f32x4 a = ((const f32x4*)s)[0], b = ((const f32x4*)s)[1];
        unsigned int hb[8], lb[8];
        float v[8] = {a[0], a[1], a[2], a[3], b[0], b[1], b[2], b[3]};
#pragma unroll
        for (int q = 0; q < 8; ++q) {
            hb[q] = bf16_rn(v[q]);
            lb[q] = bf16_rn(v[q] - bf16f(hb[q]));
        }
        uint4 oh, ol;
        oh.x = hb[0] | (hb[1] << 16); oh.y = hb[2] | (hb[3] << 16);
        oh.z = hb[4] | (hb[5] << 16); oh.w = hb[6] | (hb[7] << 16);
        ol.x = lb[0] | (lb[1] << 16); ol.y = lb[2] | (lb[3] << 16);
        ol.z = lb[4] | (lb[5] << 16); ol.w = lb[6] | (lb[7] << 16);
        const size_t idx = ubase + (size_t)h * 8192 + row * 32 + slot * 8;
        *(uint4*)(panA + idx)  = oh;
        *(uint4*)(panAl + idx) = ol;
    }
}

// ---------------------------------------------------------------------------
// Prepass 2: We1[e][k][d] fp32 -> panB[nbG(64)][TT(128)]{16KB unit}.
// ---------------------------------------------------------------------------
__global__ __launch_bounds__(256) void build_w1B_panels(
    const float* __restrict__ We1, unsigned short* __restrict__ panB)
{
    __shared__ unsigned short tile[64][72];
    const int dblk = blockIdx.x, t = blockIdx.y, e = blockIdx.z;
    const int tid = threadIdx.x;
    {
        const int kr = tid >> 2, c0 = (tid & 3) * 16;
        const float* s = We1 + ((size_t)e * H_DIM + t * 64 + kr) * H2_DIM
                             + dblk * 64 + c0;
#pragma unroll
        for (int q = 0; q < 4; ++q) {
            f32x4 v = ((const f32x4*)s)[q];
            tile[kr][c0 + q * 4 + 0] = (unsigned short)bf16_rn(v[0]);
            tile[kr][c0 + q * 4 + 1] = (unsigned short)bf16_rn(v[1]);
            tile[kr][c0 + q * 4 + 2] = (unsigned short)bf16_rn(v[2]);
            tile[kr][c0 + q * 4 + 3] = (unsigned short)bf16_rn(v[3]);
        }
    }
    __syncthreads();
    const int nbG = e * 8 + (dblk >> 2);
    const int col = tid >> 2, slot = tid & 3;
    const int colg = (dblk & 3) * 64 + col;
    const int kslot = slot ^ ((colg >> 1) & 3);
#pragma unroll
    for (int hh = 0; hh < 2; ++hh) {
        const int kl = hh * 32 + kslot * 8;
        uint4 o;
        o.x = (unsigned int)tile[kl + 0][col] | ((unsigned int)tile[kl + 1][col] << 16);
        o.y = (unsigned int)tile[kl + 2][col] | ((unsigned int)tile[kl + 3][col] << 16);
        o.z = (unsigned int)tile[kl + 4][col] | ((unsigned int)tile[kl + 5][col] << 16);
        o.w = (unsigned int)tile[kl + 6][col] | ((unsigned int)tile[kl + 7][col] << 16);
        *(uint4*)(panB + (((size_t)nbG * 64 + t) * 2 + hh) * 8192
                        + colg * 32 + slot * 8) = o;
    }
}

// ---------------------------------------------------------------------------
// Prepass 3: Wg1 -> panBgh/panBgl hi/lo panels (gate).
// ---------------------------------------------------------------------------
__global__ __launch_bounds__(256) void build_wg1_panels(
    const float* __restrict__ Wg1, unsigned short* __restrict__ panBgh,
    unsigned short* __restrict__ panBgl)
{
    __shared__ unsigned short tileH[64][72];
    __shared__ unsigned short tileL[64][72];
    const int dblk = blockIdx.x, t = blockIdx.y;
    const int tid = threadIdx.x;
    {
        const int kr = tid >> 2, c0 = (tid & 3) * 16;
        const float* s = Wg1 + ((size_t)t * 64 + kr) * H2_DIM + dblk * 64 + c0;
#pragma unroll
        for (int q = 0; q < 4; ++q) {
            f32x4 v = ((const f32x4*)s)[q];
#pragma unroll
            for (int j = 0; j < 4; ++j) {
                const unsigned int hb = bf16_rn(v[j]);
                tileH[kr][c0 + q * 4 + j] = (unsigned short)hb;
                tileL[kr][c0 + q * 4 + j] =
                    (unsigned short)bf16_rn(v[j] - bf16f(hb));
            }
        }
    }
    __syncthreads();
    const int nbG = dblk >> 1;
    const int col = tid >> 2, slot = tid & 3;
    const int colg = (dblk & 1) * 64 + col;
    const int kslot = slot ^ ((colg >> 1) & 3);
#pragma unroll
    for (int hh = 0; hh < 2; ++hh) {
        const int kl = hh * 32 + kslot * 8;
        uint4 oh, ol;
        oh.x = (unsigned int)tileH[kl + 0][col] | ((unsigned int)tileH[kl + 1][col] << 16);
        oh.y = (unsigned int)tileH[kl + 2][col] | ((unsigned int)tileH[kl + 3][col] << 16);
        oh.z = (unsigned int)tileH[kl + 4][col] | ((unsigned int)tileH[kl + 5][col] << 16);
        oh.w = (unsigned int)tileH[kl + 6][col] | ((unsigned int)tileH[kl + 7][col] << 16);
        ol.x = (unsigned int)tileL[kl + 0][col] | ((unsigned int)tileL[kl + 1][col] << 16);
        ol.y = (unsigned int)tileL[kl + 2][col] | ((unsigned int)tileL[kl + 3][col] << 16);
        ol.z = (unsigned int)tileL[kl + 4][col] | ((unsigned int)tileL[kl + 5][col] << 16);
        ol.w = (unsigned int)tileL[kl + 6][col] | ((unsigned int)tileL[kl + 7][col] << 16);
        const size_t idx = (((size_t)nbG * 64 + t) * 2 + hh) * 4096
                         + colg * 32 + slot * 8;
        *(uint4*)(panBgh + idx) = oh;
        *(uint4*)(panBgl + idx) = ol;
    }
}

// ---------------------------------------------------------------------------
// Gate GEMM (panel-fed, single-buffer) — R16 verified (688us, 3 blocks/CU).
// ---------------------------------------------------------------------------
__global__ __launch_bounds__(256, 3) void moe_gate_panel(
    const unsigned short* __restrict__ panA, const unsigned short* __restrict__ panAl,
    const unsigned short* __restrict__ panBgh, const unsigned short* __restrict__ panBgl,
    const float* __restrict__ bg1, const float* __restrict__ Wg2,
    float* __restrict__ gpart)
{
    __shared__ short lAh[4096], lAl[4096];
    __shared__ short lBh[4096], lBl[4096];
    __shared__ float lW2[128 * 8];
    __shared__ float gred[2][128][8];

    const int tid  = threadIdx.x;
    const int lane = tid & 63;
    const int wv   = tid >> 6;
    const int wm   = wv >> 1;
    const int wn   = wv & 1;
    const int nb = blockIdx.x;
    const int bm = blockIdx.y;
    const int dbase = nb * 128;

    const char* AhB = (const char*)panA  + ((size_t)(bm >> 1) << 21)
                                         + ((size_t)(bm & 1) << 13);
    const char* AlB = (const char*)panAl + ((size_t)(bm >> 1) << 21)
                                         + ((size_t)(bm & 1) << 13);
    const char* BhB = (const char*)panBgh + ((size_t)nb << 20);
    const char* BlB = (const char*)panBgl + ((size_t)nb << 20);

    {
        const f32x4* s = reinterpret_cast<const f32x4*>(Wg2 + (size_t)dbase * 8);
        reinterpret_cast<f32x4*>(lW2)[tid] = s[tid];
    }

    const int rA = wm * 64 + (lane & 15);
    const int offA = rA * 64 + ((((lane >> 4)) ^ ((rA >> 1) & 3)) << 4);
    const int rB = wn * 64 + (lane & 15);
    const int offB = rB * 64 + ((((lane >> 4)) ^ ((rB >> 1) & 3)) << 4);

    f32x4 acc[4][4];
#pragma unroll
    for (int i = 0; i < 4; ++i)
#pragma unroll
        for (int j = 0; j < 4; ++j) acc[i][j] = (f32x4){0.f, 0.f, 0.f, 0.f};

#define GRD8(BASE, OFF) \
    (*reinterpret_cast<const short8*>(reinterpret_cast<const char*>(BASE) + (OFF)))

    for (int t = 0; t < 128; ++t) {
        __syncthreads();
        {
            const char* ua = AhB + ((size_t)t << 14);
            gload_lds16(ua + tid * 16,        (char*)lAh + wv * 1024);
            gload_lds16(ua + 4096 + tid * 16, (char*)lAh + 4096 + wv * 1024);
            const char* ul = AlB + ((size_t)t << 14);
            gload_lds16(ul + tid * 16,        (char*)lAl + wv * 1024);
            gload_lds16(ul + 4096 + tid * 16, (char*)lAl + 4096 + wv * 1024);
            const char* ub = BhB + ((size_t)t << 13);
            gload_lds16(ub + tid * 16,        (char*)lBh + wv * 1024);
            gload_lds16(ub + 4096 + tid * 16, (char*)lBh + 4096 + wv * 1024);
            const char* vb = BlB + ((size_t)t << 13);
            gload_lds16(vb + tid * 16,        (char*)lBl + wv * 1024);
            gload_lds16(vb + 4096 + tid * 16, (char*)lBl + 4096 + wv * 1024);
        }
        __syncthreads();

        short8 ah[4], al[4], bh[4], bl[4];
#pragma unroll
        for (int i = 0; i < 4; ++i) {
            ah[i] = GRD8(lAh, offA + i * 1024);
            al[i] = GRD8(lAl, offA + i * 1024);
        }
#pragma unroll
        for (int n = 0; n < 4; ++n) {
            bh[n] = GRD8(lBh, offB + n * 1024);
            bl[n] = GRD8(lBl, offB + n * 1024);
        }
        __builtin_amdgcn_s_setprio(1);
#pragma unroll
        for (int i = 0; i < 4; ++i)
#pragma unroll
            for (int n = 0; n < 4; ++n) {
                acc[i][n] = __builtin_amdgcn_mfma_f32_16x16x32_bf16(ah[i], bh[n], acc[i][n], 0, 0, 0);
                acc[i][n] = __builtin_amdgcn_mfma_f32_16x16x32_bf16(ah[i], bl[n], acc[i][n], 0, 0, 0);
                acc[i][n] = __builtin_amdgcn_mfma_f32_16x16x32_bf16(al[i], bh[n], acc[i][n], 0, 0, 0);
            }
        __builtin_amdgcn_s_setprio(0);
    }
#undef GRD8

    const int c = lane & 15, g = lane >> 4;
    float bgv[4];
#pragma unroll
    for (int ni = 0; ni < 4; ++ni) bgv[ni] = bg1[dbase + wn * 64 + ni * 16 + c];
#pragma unroll
    for (int mi = 0; mi < 4; ++mi) {
#pragma unroll
        for (int r = 0; r < 4; ++r) {
            float gv[4];
#pragma unroll
            for (int ni = 0; ni < 4; ++ni)
                gv[ni] = fmaxf(acc[mi][ni][r] + bgv[ni], 0.f);
#pragma unroll
            for (int e8 = 0; e8 < 8; ++e8) {
                float tsum = 0.f;
#pragma unroll
                for (int ni = 0; ni < 4; ++ni)
                    tsum = fmaf(gv[ni], lW2[(wn * 64 + ni * 16 + c) * 8 + e8], tsum);
                tsum += __shfl_xor(tsum, 1);
                tsum += __shfl_xor(tsum, 2);
                tsum += __shfl_xor(tsum, 4);
                tsum += __shfl_xor(tsum, 8);
                if (c == e8) gred[wn][wm * 64 + mi * 16 + g * 4 + r][e8] = tsum;
            }
        }
    }
    __syncthreads();
    {
        const int row = tid & 127;
        const int ebase = (tid >> 7) * 4;
        const int b = bm * 128 + row;
#pragma unroll
        for (int i = 0; i < 4; ++i) {
            const int e8 = ebase + i;
            gpart[(size_t)b * 128 + nb * 8 + e8] =
                gred[0][row][e8] + gred[1][row][e8];
        }
    }
}

// ---------------------------------------------------------------------------
// Routing: zero counters; logits+top2+list build; tile table.
// ---------------------------------------------------------------------------
__global__ void route_zero(int* __restrict__ cnt) {
    if (threadIdx.x < E_DIM) cnt[threadIdx.x] = 0;
}

__global__ __launch_bounds__(256) void moe_logits_topk(
    const float* __restrict__ gpart, const float* __restrict__ bg2,
    int* __restrict__ sel, float* __restrict__ w2f,
    int* __restrict__ cnt, int* __restrict__ tokenlist)
{
    const int b = blockIdx.x * 256 + threadIdx.x;
    float logit[8];
#pragma unroll
    for (int e = 0; e < 8; ++e) logit[e] = bg2[e];
    const float* gp = gpart + (size_t)b * 128;
#pragma unroll
    for (int cN = 0; cN < 16; ++cN)
#pragma unroll
        for (int e = 0; e < 8; ++e) logit[e] += gp[cN * 8 + e];

    int i1 = 0; float m1 = logit[0];
#pragma unroll
    for (int e = 1; e < 8; ++e) if (logit[e] > m1) { m1 = logit[e]; i1 = e; }
    int i2 = -1; float m2 = -3.4e38f;
#pragma unroll
    for (int e = 0; e < 8; ++e) if (e != i1 && logit[e] > m2) { m2 = logit[e]; i2 = e; }

    sel[b] = i1 | (i2 << 8);
    w2f[b] = expf(m2 - m1);
    const int p1 = atomicAdd(&cnt[i1], 1);
    tokenlist[i1 * B_DIM + p1] = (b << 1);
    const int p2 = atomicAdd(&cnt[i2], 1);
    tokenlist[i2 * B_DIM + p2] = (b << 1) | 1;
}

__global__ void moe_tiletab(
    const int* __restrict__ cnt, int* __restrict__ tileE,
    int* __restrict__ tileB, int* __restrict__ nTiles)
{
    if (threadIdx.x == 0) {
        int tot = 0;
        for (int e = 0; e < E_DIM; ++e) {
            const int nt = (cnt[e] + 127) >> 7;
            for (int j = 0; j < nt; ++j) { tileE[tot] = e; tileB[tot] = j; ++tot; }
        }
        *nTiles = tot;
    }
}

// ---------------------------------------------------------------------------
// Sparse expert GEMM R18: 4-buffer rotation, stage-ahead 3, counted vmcnt(6)
// (covers ~900cyc scattered gathered-A latency), chunk-fastest grid.
// Output esel[token][slot(2)][chunk(8)].
// ---------------------------------------------------------------------------
__global__ __launch_bounds__(512, 4) void moe_expert_sparse(
    const unsigned short* __restrict__ panA, const unsigned short* __restrict__ panB,
    const float* __restrict__ be1, const float* __restrict__ We2,
    const int* __restrict__ tileE, const int* __restrict__ tileB,
    const int* __restrict__ nTiles, const int* __restrict__ cnt,
    const int* __restrict__ tokenlist, float* __restrict__ esel)
{
    __shared__ short lA[4][4096];    // 16KB
    __shared__ short lB[4][8192];    // 32KB
    __shared__ float red[4][128];
    __shared__ int   tokbuf[128];

    const int tix = blockIdx.y;
    if (tix >= *nTiles) return;       // uniform exit before any barrier
    const int chunk = blockIdx.x;

    const int tid  = threadIdx.x;
    const int lane = tid & 63;
    const int wv   = tid >> 6;
    const int wm   = wv >> 2;
    const int wn   = wv & 3;

    const int e  = tileE[tix];
    const int tb = tileB[tix];
    const int ce = cnt[e];
    const int nb = e * 8 + chunk;
    const int dbase = chunk * 256;

    if (tid < 128) {
        const int gi = tb * 128 + tid;
        tokbuf[tid] = (gi < ce) ? tokenlist[e * B_DIM + gi] : -1;
    }
    __syncthreads();

    // per-thread gathered A source (swizzle corrected per token row)
    const int rawT = tokbuf[tid >> 2];
    const int tokv = ((rawT < 0) ? tokbuf[0] : rawT) >> 1;
    const int trow = tokv & 255;
    const int lr = tid >> 2, ls = tid & 3;
    const int sslot = ls ^ ((lr >> 1) & 3) ^ ((trow >> 1) & 3);
    const char* Asrc = (const char*)panA + ((size_t)(tokv >> 8) << 21)
                     + trow * 64 + sslot * 16;
    const char* Bbase = (const char*)panB + ((size_t)nb << 21);

#define STAGE(TT, CC) do {                                                     \
    gload_lds16(Asrc + ((size_t)(TT) << 14), (char*)&lA[CC][0] + wv * 1024);   \
    const char* ub_ = Bbase + ((size_t)(TT) << 14);                            \
    gload_lds16(ub_ + tid * 16, (char*)&lB[CC][0] + wv * 1024);                \
    gload_lds16(ub_ + 8192 + tid * 16, (char*)&lB[CC][0] + 8192 + wv * 1024);  \
} while (0)

#define RD8(BASE, OFF) \
    (*reinterpret_cast<const short8*>(reinterpret_cast<const char*>(BASE) + (OFF)))

    const int rA = wm * 64 + (lane & 15);
    const int offA = rA * 64 + ((((lane >> 4)) ^ ((rA >> 1) & 3)) << 4);
    const int rB = wn * 64 + (lane & 15);
    const int offB = rB * 64 + ((((lane >> 4)) ^ ((rB >> 1) & 3)) << 4);

    f32x4 acc[4][4];
#pragma unroll
    for (int i = 0; i < 4; ++i)
#pragma unroll
        for (int j = 0; j < 4; ++j) acc[i][j] = (f32x4){0.f, 0.f, 0.f, 0.f};

    // prologue: stage tiles 0,1,2 (9 loads); vmcnt(6) -> tile 0 landed,
    // tiles 1,2 (6 loads) in flight.
    STAGE(0, 0);
    STAGE(1, 1);
    STAGE(2, 2);
    asm volatile("s_waitcnt vmcnt(6)");
    __builtin_amdgcn_s_barrier();

// iter t: stage tile TN=t+3 -> buf (t+3)%4, read buf t%4, 16 MFMA,
// vmcnt(6) (= tile t+1's 3 loads landed; t+2,t+3's 6 in flight), barrier.
// RAW: buf t%4 staged 3 iters back, guaranteed by prior vmcnt+barrier chain.
// WAR: buf (t+3)%4 last read at iter t-1, one collective barrier earlier.
#define ITER(CUR, NXT, TN) do {                                                \
    STAGE(TN, NXT);                                                            \
    short8 af_[4], bf_[4];                                                     \
    _Pragma("unroll")                                                          \
    for (int i = 0; i < 4; ++i) af_[i] = RD8(&lA[CUR][0], offA + i * 1024);    \
    _Pragma("unroll")                                                          \
    for (int n = 0; n < 4; ++n) bf_[n] = RD8(&lB[CUR][0], offB + n * 1024);    \
    __builtin_amdgcn_s_setprio(1);                                             \
    _Pragma("unroll")                                                          \
    for (int i = 0; i < 4; ++i)                                                \
        _Pragma("unroll")                                                      \
        for (int n = 0; n < 4; ++n)                                            \
            acc[i][n] = __builtin_amdgcn_mfma_f32_16x16x32_bf16(af_[i], bf_[n], acc[i][n], 0, 0, 0); \
    __builtin_amdgcn_s_setprio(0);                                             \
    asm volatile("s_waitcnt vmcnt(6)");                                        \
    __builtin_amdgcn_s_barrier();                                              \
} while (0)

    for (int t = 0; t < 124; t += 4) {
        ITER(0, 3, t + 3);
        ITER(1, 0, t + 4);
        ITER(2, 1, t + 5);
        ITER(3, 2, t + 6);
    }
    // tails: t=124 stages real tile 127; t=125..127 dummy re-stages of 127
    // into buffers that are never read again (in-bounds, WAR-safe).
    ITER(0, 3, 127);
    ITER(1, 0, 127);
    ITER(2, 1, 127);
    ITER(3, 2, 127);
    asm volatile("s_waitcnt vmcnt(0)");   // drain dummies before block end
#undef ITER
#undef STAGE

    const int cc = lane & 15, g = lane >> 4;
    float w2v[4], b1v[4];
#pragma unroll
    for (int ni = 0; ni < 4; ++ni) {
        const int d = dbase + wn * 64 + ni * 16 + cc;
        b1v[ni] = be1[e * H2_DIM + d];
        w2v[ni] = We2[e * H2_DIM + d];
    }
#pragma unroll
    for (int mi = 0; mi < 4; ++mi) {
#pragma unroll
        for (int r = 0; r < 4; ++r) {
            float s = 0.f;
#pragma unroll
            for (int ni = 0; ni < 4; ++ni) {
                float v = acc[mi][ni][r] + b1v[ni];
                v = fmaxf(v, 0.f);
                s = fmaf(v, w2v[ni], s);
            }
            s += __shfl_xor(s, 1);
            s += __shfl_xor(s, 2);
            s += __shfl_xor(s, 4);
            s += __shfl_xor(s, 8);
            if (cc == 0) red[wn][wm * 64 + mi * 16 + g * 4 + r] = s;
        }
    }
    __syncthreads();
    if (tid < 128) {
        const int r2 = tokbuf[tid];
        if (r2 >= 0) {
            const int tk = r2 >> 1, sl = r2 & 1;
            esel[(size_t)tk * 16 + sl * 8 + chunk] =
                red[0][tid] + red[1][tid] + red[2][tid] + red[3][tid];
        }
    }
}

// ---------------------------------------------------------------------------
// Sparse finalize: combine the two selected experts.
// ---------------------------------------------------------------------------
__global__ __launch_bounds__(256) void moe_finalize_sparse(
    const float* __restrict__ esel, const int* __restrict__ sel,
    const float* __restrict__ w2f, const float* __restrict__ be2,
    float* __restrict__ out)
{
    const int b = blockIdx.x * 256 + threadIdx.x;
    const int s = sel[b];
    const int i1 = s & 255, i2 = (s >> 8) & 255;
    const float w2 = w2f[b];
    const float* ep = esel + (size_t)b * 16;
    float eo1 = be2[i1], eo2 = be2[i2];
#pragma unroll
    for (int c = 0; c < 8; ++c) eo1 += ep[c];
#pragma unroll
    for (int c = 0; c < 8; ++c) eo2 += ep[8 + c];
    out[b] = (eo1 + w2 * eo2) / (1.f + w2);
}

// ---------------------------------------------------------------------------
// Dense expert GEMM (R10 verbatim) — tier-2.
// ---------------------------------------------------------------------------
__global__ __launch_bounds__(512, 4) void moe_expert_gemm_128(
    const unsigned short* __restrict__ panA, const unsigned short* __restrict__ panB,
    const float* __restrict__ be1, const float* __restrict__ We2,
    float* __restrict__ epart)
{
    __shared__ short lA[3][4096];
    __shared__ short lB[3][8192];
    __shared__ float red[4][128];

    const int tid  = threadIdx.x;
    const int lane = tid & 63;
    const int wv   = tid >> 6;
    const int wm   = wv >> 2;
    const int wn   = wv & 3;

    const int lin = blockIdx.x;
    const int sb  = lin >> 8, i5 = lin & 255;
    const int sbm = sb & 7, snb = sb >> 3;
    const int xcd = i5 & 7, j5 = i5 >> 3;
    const int bm  = sbm * 16 + (xcd & 1) * 8 + (j5 & 7);
    const int nb  = snb * 16 + (xcd >> 1) * 4 + (j5 >> 3);
    const int e = nb >> 3, chunk = nb & 7;
    const int dbase = chunk * 256;

    const char* Abase = (const char*)panA + ((size_t)(bm >> 1) << 21)
                                          + ((size_t)(bm & 1) << 13);
    const char* Bbase = (const char*)panB + ((size_t)nb << 21);

#define STAGE(TT, CC) do {                                                     \
    const char* ua_ = Abase + ((size_t)(TT) << 14);                            \
    gload_lds16(ua_ + tid * 16, (char*)&lA[CC][0] + wv * 1024);                \
    const char* ub_ = Bbase + ((size_t)(TT) << 14);                            \
    gload_lds16(ub_ + tid * 16, (char*)&lB[CC][0] + wv * 1024);                \
    gload_lds16(ub_ + 8192 + tid * 16, (char*)&lB[CC][0] + 8192 + wv * 1024);  \
} while (0)

#define RD8(BASE, OFF) \
    (*reinterpret_cast<const short8*>(reinterpret_cast<const char*>(BASE) + (OFF)))

    const int rA = wm * 64 + (lane & 15);
    const int offA = rA * 64 + ((((lane >> 4)) ^ ((rA >> 1) & 3)) << 4);
    const int rB = wn * 64 + (lane & 15);
    const int offB = rB * 64 + ((((lane >> 4)) ^ ((rB >> 1) & 3)) << 4);

    f32x4 acc[4][4];
#pragma unroll
    for (int i = 0; i < 4; ++i)
#pragma unroll
        for (int j = 0; j < 4; ++j) acc[i][j] = (f32x4){0.f, 0.f, 0.f, 0.f};

    STAGE(0, 0);
    STAGE(1, 1);
    asm volatile("s_waitcnt vmcnt(3)");
    __builtin_amdgcn_s_barrier();

#define ITER(CUR, NXT, TN) do {                                                \
    STAGE(TN, NXT);                                                            \
    short8 af_[4], bf_[4];                                                     \
    _Pragma("unroll")                                                          \
    for (int i = 0; i < 4; ++i) af_[i] = RD8(&lA[CUR][0], offA + i * 1024);    \
    _Pragma("unroll")                                                          \
    for (int n = 0; n < 4; ++n) bf_[n] = RD8(&lB[CUR][0], offB + n * 1024);    \
    __builtin_amdgcn_s_setprio(1);                                             \
    _Pragma("unroll")                                                          \
    for (int i = 0; i < 4; ++i)                                                \
        _Pragma("unroll")                                                      \
        for (int n = 0; n < 4; ++n)                                            \
            acc[i][n] = __builtin_amdgcn_mfma_f32_16x16x32_bf16(af_[i], bf_[n], acc[i][n], 0, 0, 0); \
    __builtin_amdgcn_s_setprio(0);                                             \
    asm volatile("s_waitcnt vmcnt(3)");                                        \
    __builtin_amdgcn_s_barrier();                                              \
} while (0)

    for (int t = 0; t < 126; t += 3) {
        ITER(0, 2, t + 2);
        ITER(1, 0, t + 3);
        ITER(2, 1, t + 4);
    }
    ITER(0, 2, 127);
    ITER(1, 0, 127);
    asm volatile("s_waitcnt vmcnt(0)");
#undef ITER
#undef STAGE

    const int cc = lane & 15, g = lane >> 4;
    float w2v[4], b1v[4];
#pragma unroll
    for (int ni = 0; ni < 4; ++ni) {
        const int d = dbase + wn * 64 + ni * 16 + cc;
        b1v[ni] = be1[e * H2_DIM + d];
        w2v[ni] = We2[e * H2_DIM + d];
    }
#pragma unroll
    for (int mi = 0; mi < 4; ++mi) {
#pragma unroll
        for (int r = 0; r < 4; ++r) {
            float s = 0.f;
#pragma unroll
            for (int ni = 0; ni < 4; ++ni) {
                float v = acc[mi][ni][r] + b1v[ni];
                v = fmaxf(v, 0.f);
                s = fmaf(v, w2v[ni], s);
            }
            s += __shfl_xor(s, 1);
            s += __shfl_xor(s, 2);
            s += __shfl_xor(s, 4);
            s += __shfl_xor(s, 8);
            if (cc == 0) red[wn][wm * 64 + mi * 16 + g * 4 + r] = s;
        }
    }
    __syncthreads();
    if (tid < 128) {
        const int b = bm * 128 + tid;
        epart[((size_t)b * E_DIM + e) * 8 + chunk] =
            red[0][tid] + red[1][tid] + red[2][tid] + red[3][tid];
    }
}

// ---------------------------------------------------------------------------
// Fallback gate GEMM (fp32 in-kernel split) — round-1 verified. [tier-2/3]
// ---------------------------------------------------------------------------
__global__ __launch_bounds__(256, 2) void moe_gate_gemm(
    const float* __restrict__ x, const float* __restrict__ Wg1,
    const float* __restrict__ bg1, const float* __restrict__ Wg2,
    float* __restrict__ gpart)
{
    __shared__ short lAh[128 * 64], lAl[128 * 64];
    __shared__ short lBh[128 * 64], lBl[128 * 64];
    __shared__ float lW2[128 * 8];
    __shared__ float gred[2][128][8];

    const int tid  = threadIdx.x;
    const int lane = tid & 63;
    const int wm = (tid >> 6) >> 1, wn = (tid >> 6) & 1;
    const int nb = blockIdx.x, bm = blockIdx.y;
    const int dbase = nb * 128;

    const float* Asrc = x + (size_t)bm * 128 * H_DIM;
    const float* Bsrc = Wg1 + dbase;

    {
        const f32x4* s = reinterpret_cast<const f32x4*>(Wg2 + (size_t)dbase * 8);
        reinterpret_cast<f32x4*>(lW2)[tid] = s[tid];
    }

    f32x4 acc[4][4];
#pragma unroll
    for (int i = 0; i < 4; ++i)
#pragma unroll
        for (int j = 0; j < 4; ++j) acc[i][j] = (f32x4){0.f, 0.f, 0.f, 0.f};

    const int arow0 = tid >> 4, af4 = tid & 15;
    const int bn = tid & 127, bkc0 = tid >> 7;

    for (int k0 = 0; k0 < H_DIM; k0 += 64) {
        __syncthreads();
#pragma unroll
        for (int j = 0; j < 8; ++j) {
            const int row = arow0 + j * 16;
            const float* p = Asrc + (size_t)row * H_DIM + k0 + af4 * 4;
            float a[4] = {p[0], p[1], p[2], p[3]};
            unsigned int hb[4], lb[4];
#pragma unroll
            for (int q = 0; q < 4; ++q) {
                hb[q] = bf16_rn(a[q]);
                lb[q] = bf16_rn(a[q] - bf16f(hb[q]));
            }
            const int byte = row * 128 + ((af4 * 8) ^ ((row & 7) << 4));
            *reinterpret_cast<uint2*>(reinterpret_cast<char*>(lAh) + byte) =
                make_uint2(hb[0] | (hb[1] << 16), hb[2] | (hb[3] << 16));
            *reinterpret_cast<uint2*>(reinterpret_cast<char*>(lAl) + byte) =
                make_uint2(lb[0] | (lb[1] << 16), lb[2] | (lb[3] << 16));
        }
#pragma unroll
        for (int j = 0; j < 4; ++j) {
            const int kc = bkc0 + 2 * j;
            const float* p = Bsrc + (size_t)(k0 + kc * 8) * H2_DIM + bn;
            unsigned int hb[8], lb[8];
#pragma unroll
            for (int q = 0; q < 8; ++q) {
                float v = p[(size_t)q * H2_DIM];
                hb[q] = bf16_rn(v);
                lb[q] = bf16_rn(v - bf16f(hb[q]));
            }
            const int byte = bn * 128 + ((kc * 16) ^ ((bn & 7) << 4));
            *reinterpret_cast<uint4*>(reinterpret_cast<char*>(lBh) + byte) =
                make_uint4(hb[0] | (hb[1] << 16), hb[2] | (hb[3] << 16),
                           hb[4] | (hb[5] << 16), hb[6] | (hb[7] << 16));
            *reinterpret_cast<uint4*>(reinterpret_cast<char*>(lBl) + byte) =
                make_uint4(lb[0] | (lb[1] << 16), lb[2] | (lb[3] << 16),
                           lb[4] | (lb[5] << 16), lb[6] | (lb[7] << 16));
        }
        __syncthreads();
#pragma unroll
        for (int kk = 0; kk < 2; ++kk) {
            const int kbyte = kk * 64 + ((lane >> 4) << 4);
            short8 ah[4], al[4], bh[4], bl[4];
#pragma unroll
            for (int mi = 0; mi < 4; ++mi) {
                const int r = wm * 64 + mi * 16 + (lane & 15);
                const int off = r * 128 + (kbyte ^ ((r & 7) << 4));
                ah[mi] = *reinterpret_cast<const short8*>(reinterpret_cast<const char*>(lAh) + off);
                al[mi] = *reinterpret_cast<const short8*>(reinterpret_cast<const char*>(lAl) + off);
            }
#pragma unroll
            for (int ni = 0; ni < 4; ++ni) {
                const int r = wn * 64 + ni * 16 + (lane & 15);
                const int off = r * 128 + (kbyte ^ ((r & 7) << 4));
                bh[ni] = *reinterpret_cast<const short8*>(reinterpret_cast<const char*>(lBh) + off);
                bl[ni] = *reinterpret_cast<const short8*>(reinterpret_cast<const char*>(lBl) + off);
            }
#pragma unroll
            for (int mi = 0; mi < 4; ++mi)
#pragma unroll
                for (int ni = 0; ni < 4; ++ni) {
                    acc[mi][ni] = __builtin_amdgcn_mfma_f32_16x16x32_bf16(ah[mi], bh[ni], acc[mi][ni], 0, 0, 0);
                    acc[mi][ni] = __builtin_amdgcn_mfma_f32_16x16x32_bf16(ah[mi], bl[ni], acc[mi][ni], 0, 0, 0);
                    acc[mi][ni] = __builtin_amdgcn_mfma_f32_16x16x32_bf16(al[mi], bh[ni], acc[mi][ni], 0, 0, 0);
                }
        }
    }

    const int c = lane & 15, g = lane >> 4;
    float bgv[4];
#pragma unroll
    for (int ni = 0; ni < 4; ++ni) bgv[ni] = bg1[dbase + wn * 64 + ni * 16 + c];
#pragma unroll
    for (int mi = 0; mi < 4; ++mi) {
#pragma unroll
        for (int r = 0; r < 4; ++r) {
            float gv[4];
#pragma unroll
            for (int ni = 0; ni < 4; ++ni)
                gv[ni] = fmaxf(acc[mi][ni][r] + bgv[ni], 0.f);
#pragma unroll
            for (int e8 = 0; e8 < 8; ++e8) {
                float t = 0.f;
#pragma unroll
                for (int ni = 0; ni < 4; ++ni)
                    t = fmaf(gv[ni], lW2[(wn * 64 + ni * 16 + c) * 8 + e8], t);
                t += __shfl_xor(t, 1);
                t += __shfl_xor(t, 2);
                t += __shfl_xor(t, 4);
                t += __shfl_xor(t, 8);
                if (c == e8) gred[wn][wm * 64 + mi * 16 + g * 4 + r][e8] = t;
            }
        }
    }
    __syncthreads();
    {
        const int row = tid & 127;
        const int ebase = (tid >> 7) * 4;
        const int b = bm * 128 + row;
#pragma unroll
        for (int i = 0; i < 4; ++i) {
            const int e8 = ebase + i;
            gpart[(size_t)b * 128 + nb * 8 + e8] = gred[0][row][e8] + gred[1][row][e8];
        }
    }
}

// ---------------------------------------------------------------------------
// Fallback expert GEMM (fp32 in-kernel conversion) — round-1 verified. [tier-3]
// ---------------------------------------------------------------------------
__global__ __launch_bounds__(256, 2) void moe_expert_gemm(
    const float* __restrict__ x, const float* __restrict__ We1,
    const float* __restrict__ be1, const float* __restrict__ We2,
    float* __restrict__ epart)
{
    __shared__ short lA[128 * 64];
    __shared__ short lB[128 * 64];
    __shared__ float red[2][128];

    const int tid  = threadIdx.x;
    const int lane = tid & 63;
    const int wm   = (tid >> 6) >> 1;
    const int wn   = (tid >> 6) & 1;
    const int nb = blockIdx.x, bm = blockIdx.y;
    const int e = nb >> 4, chunk = nb & 15;
    const int dbase = chunk * 128;

    const float* Asrc = x + (size_t)bm * 128 * H_DIM;
    const float* Bsrc = We1 + (size_t)e * H_DIM * H2_DIM + dbase;

    f32x4 acc[4][4];
#pragma unroll
    for (int i = 0; i < 4; ++i)
#pragma unroll
        for (int j = 0; j < 4; ++j) acc[i][j] = (f32x4){0.f, 0.f, 0.f, 0.f};

    const int arow0 = tid >> 4, af4 = tid & 15;
    const int bn = tid & 127, bkc0 = tid >> 7;

    for (int k0 = 0; k0 < H_DIM; k0 += 64) {
        __syncthreads();
#pragma unroll
        for (int j = 0; j < 8; ++j) {
            const int row = arow0 + j * 16;
            const float* p = Asrc + (size_t)row * H_DIM + k0 + af4 * 4;
            float a0 = p[0], a1 = p[1], a2 = p[2], a3 = p[3];
            uint2 wv2;
            wv2.x = bf16_rn(a0) | (bf16_rn(a1) << 16);
            wv2.y = bf16_rn(a2) | (bf16_rn(a3) << 16);
            const int byte = row * 128 + ((af4 * 8) ^ ((row & 7) << 4));
            *reinterpret_cast<uint2*>(reinterpret_cast<char*>(lA) + byte) = wv2;
        }
#pragma unroll
        for (int j = 0; j < 4; ++j) {
            const int kc = bkc0 + 2 * j;
            const float* p = Bsrc + (size_t)(k0 + kc * 8) * H2_DIM + bn;
            uint4 wv4;
            wv4.x = bf16_rn(p[0])          | (bf16_rn(p[H2_DIM])     << 16);
            wv4.y = bf16_rn(p[2 * H2_DIM]) | (bf16_rn(p[3 * H2_DIM]) << 16);
            wv4.z = bf16_rn(p[4 * H2_DIM]) | (bf16_rn(p[5 * H2_DIM]) << 16);
            wv4.w = bf16_rn(p[6 * H2_DIM]) | (bf16_rn(p[7 * H2_DIM]) << 16);
            const int byte = bn * 128 + ((kc * 16) ^ ((bn & 7) << 4));
            *reinterpret_cast<uint4*>(reinterpret_cast<char*>(lB) + byte) = wv4;
        }
        __syncthreads();
#pragma unroll
        for (int kk = 0; kk < 2; ++kk) {
            const int kbyte = kk * 64 + ((lane >> 4) << 4);
            short8 af[4], bfr[4];
#pragma unroll
            for (int mi = 0; mi < 4; ++mi) {
                const int r = wm * 64 + mi * 16 + (lane & 15);
                af[mi] = *reinterpret_cast<const short8*>(
                    reinterpret_cast<const char*>(lA) + r * 128 + (kbyte ^ ((r & 7) << 4)));
            }
#pragma unroll
            for (int ni = 0; ni < 4; ++ni) {
                const int r = wn * 64 + ni * 16 + (lane & 15);
                bfr[ni] = *reinterpret_cast<const short8*>(
                    reinterpret_cast<const char*>(lB) + r * 128 + (kbyte ^ ((r & 7) << 4)));
            }
#pragma unroll
            for (int mi = 0; mi < 4; ++mi)
#pragma unroll
                for (int ni = 0; ni < 4; ++ni)
                    acc[mi][ni] = __builtin_amdgcn_mfma_f32_16x16x32_bf16(
                        af[mi], bfr[ni], acc[mi][ni], 0, 0, 0);
        }
    }

    const int c = lane & 15, g = lane >> 4;
    float w2v[4], b1v[4];
#pragma unroll
    for (int ni = 0; ni < 4; ++ni) {
        const int d = dbase + wn * 64 + ni * 16 + c;
        b1v[ni] = be1[e * H2_DIM + d];
        w2v[ni] = We2[e * H2_DIM + d];
    }
#pragma unroll
    for (int mi = 0; mi < 4; ++mi) {
#pragma unroll
        for (int r = 0; r < 4; ++r) {
            float s = 0.f;
#pragma unroll
            for (int ni = 0; ni < 4; ++ni) {
                float v = acc[mi][ni][r] + b1v[ni];
                v = fmaxf(v, 0.f);
                s = fmaf(v, w2v[ni], s);
            }
            s += __shfl_xor(s, 1);
            s += __shfl_xor(s, 2);
            s += __shfl_xor(s, 4);
            s += __shfl_xor(s, 8);
            if (c == 0) red[wn][wm * 64 + mi * 16 + g * 4 + r] = s;
        }
    }
    __syncthreads();
    if (tid < 128) {
        const int b = bm * 128 + tid;
        epart[((size_t)b * E_DIM + e) * 16 + chunk] = red[0][tid] + red[1][tid];
    }
}

// ---------------------------------------------------------------------------
// Dense finalize — tiers 2/3.
// ---------------------------------------------------------------------------
template <int NC>
__global__ __launch_bounds__(256) void moe_finalize(
    const float* __restrict__ gpart, const float* __restrict__ epart,
    const float* __restrict__ bg2, const float* __restrict__ be2,
    float* __restrict__ out)
{
    const int b = blockIdx.x * 256 + threadIdx.x;
    float logit[8];
#pragma unroll
    for (int e = 0; e < 8; ++e) logit[e] = bg2[e];
    const float* gp = gpart + (size_t)b * 128;
#pragma unroll
    for (int cN = 0; cN < 16; ++cN)
#pragma unroll
        for (int e = 0; e < 8; ++e) logit[e] += gp[cN * 8 + e];

    float eo[8];
    const float* ep = epart + (size_t)b * E_DIM * NC;
#pragma unroll
    for (int e = 0; e < 8; ++e) {
        float s = be2[e];
#pragma unroll
        for (int cN = 0; cN < NC; ++cN) s += ep[e * NC + cN];
        eo[e] = s;
    }

    int i1 = 0; float m1 = logit[0];
#pragma unroll
    for (int e = 1; e < 8; ++e) if (logit[e] > m1) { m1 = logit[e]; i1 = e; }
    int i2 = -1; float m2 = -3.4e38f;
#pragma unroll
    for (int e = 0; e < 8; ++e) if (e != i1 && logit[e] > m2) { m2 = logit[e]; i2 = e; }

    const float w2 = expf(m2 - m1);
    out[b] = (eo[i1] + w2 * eo[i2]) / (1.f + w2);
}

// ---------------------------------------------------------------------------
extern "C" void kernel_launch(void* const* d_in, const int* in_sizes, int n_in,
                              void* d_out, int out_size, void* d_ws, size_t ws_size,
                              hipStream_t stream) {
    (void)in_sizes; (void)n_in; (void)out_size;
    const float* x   = (const float*)d_in[0];
    const float* We1 = (const float*)d_in[1];
    const float* be1 = (const float*)d_in[2];
    const float* We2 = (const float*)d_in[3];
    const float* be2 = (const float*)d_in[4];
    const float* Wg1 = (const float*)d_in[5];
    const float* bg1 = (const float*)d_in[6];
    const float* Wg2 = (const float*)d_in[7];
    const float* bg2 = (const float*)d_in[8];
    float* out = (float*)d_out;

    char* ws = (char*)d_ws;
    size_t off = 0;
    float* gpart = (float*)(ws + off);                  off += (size_t)B_DIM * 128 * 4;            // 8 MB
    float* epart = (float*)(ws + off);                  off += (size_t)B_DIM * 128 * 4;            // 8 MB (esel front 1MB)
    unsigned short* panA = (unsigned short*)(ws + off); off += (size_t)B_DIM * H_DIM * 2;          // 128 MB
    unsigned short* panB = (unsigned short*)(ws + off); off += (size_t)E_DIM * H2_DIM * H_DIM * 2; // 128 MB
    const size_t NEED2 = off;
    unsigned short* panAl  = (unsigned short*)(ws + off); off += (size_t)B_DIM * H_DIM * 2;        // 128 MB
    unsigned short* panBgh = (unsigned short*)(ws + off); off += (size_t)H2_DIM * H_DIM * 2;       // 16 MB
    unsigned short* panBgl = (unsigned short*)(ws + off); off += (size_t)H2_DIM * H_DIM * 2;       // 16 MB
    int*   cnt       = (int*)(ws + off);   off += 256;
    int*   nTiles    = (int*)(ws + off);   off += 256;
    int*   tileE     = (int*)(ws + off);   off += 272 * 4;
    int*   tileB     = (int*)(ws + off);   off += 272 * 4;
    int*   sel       = (int*)(ws + off);   off += (size_t)B_DIM * 4;          // 64 KB
    float* w2f       = (float*)(ws + off); off += (size_t)B_DIM * 4;          // 64 KB
    int*   tokenlist = (int*)(ws + off);   off += (size_t)E_DIM * B_DIM * 4;  // 512 KB
    const size_t NEED1 = off;
    float* esel = epart;

    if (ws_size >= NEED1) {
        build_xA_panels_hl<<<dim3(64, 64), 256, 0, stream>>>(x, panA, panAl);
        build_wg1_panels<<<dim3(32, 64), 256, 0, stream>>>(Wg1, panBgh, panBgl);
        route_zero<<<1, 64, 0, stream>>>(cnt);
        moe_gate_panel<<<dim3(16, 128), 256, 0, stream>>>(panA, panAl, panBgh, panBgl,
                                                          bg1, Wg2, gpart);
        moe_logits_topk<<<64, 256, 0, stream>>>(gpart, bg2, sel, w2f, cnt, tokenlist);
        build_w1B_panels<<<dim3(32, 64, 8), 256, 0, stream>>>(We1, panB);  // panB L3-hot
        moe_tiletab<<<1, 64, 0, stream>>>(cnt, tileE, tileB, nTiles);
        moe_expert_sparse<<<dim3(8, 264), 512, 0, stream>>>(
            panA, panB, be1, We2, tileE, tileB, nTiles, cnt, tokenlist, esel);
        moe_finalize_sparse<<<64, 256, 0, stream>>>(esel, sel, w2f, be2, out);
    } else if (ws_size >= NEED2) {
        build_xA_panels<<<dim3(64, 64), 256, 0, stream>>>(x, panA);
        build_w1B_panels<<<dim3(32, 64, 8), 256, 0, stream>>>(We1, panB);
        moe_expert_gemm_128<<<8192, 512, 0, stream>>>(panA, panB, be1, We2, epart);
        moe_gate_gemm<<<dim3(16, 128), 256, 0, stream>>>(x, Wg1, bg1, Wg2, gpart);
        moe_finalize<8><<<64, 256, 0, stream>>>(gpart, epart, bg2, be2, out);
    } else {
        moe_expert_gemm<<<dim3(128, 128), 256, 0, stream>>>(x, We1, be1, We2, epart);
        moe_gate_gemm<<<dim3(16, 128), 256, 0, stream>>>(x, Wg1, bg1, Wg2, gpart);
        moe_finalize<16><<<64, 256, 0, stream>>>(gpart, epart, bg2, be2, out);
    }
}

// Round 19
// 1639.891 us; speedup vs baseline: 1.1208x; 1.1208x over previous
//
#include <hip/hip_runtime.h>
#include <hip/hip_bf16.h>
#include <stdint.h>

// MoE head R19 = composition of best-measured variants:
//  - gate: R16 single-buffer panel GEMM (3 blocks/CU, 688us measured)
//  - sparse expert: R16 3-buffer stage-ahead-2 vmcnt(3), chunk-fastest grid
//    (75.5KB LDS -> 2 blocks/CU; R18's 4-buffer hit 98.5KB -> 1 block/CU and
//    regressed 855us)
//  - launch order: build_w1B AFTER gate/topk (R18: panB L3-hot, FETCH
//    2.35 -> 1.91 GB)
// Tiers: ws>=NEED1 sparse; >=NEED2 dense R10; else R1 fallback.

#define B_DIM  16384
#define H_DIM  4096
#define H2_DIM 2048
#define E_DIM  8

typedef __attribute__((ext_vector_type(8))) short short8;
typedef __attribute__((ext_vector_type(4))) float f32x4;

static __device__ __forceinline__ unsigned int bf16_rn(float f) {
    unsigned int u = __builtin_bit_cast(unsigned int, f);
    u += 0x7FFFu + ((u >> 16) & 1u);
    return u >> 16;
}
static __device__ __forceinline__ float bf16f(unsigned int h) {
    unsigned int u = h << 16;
    return __builtin_bit_cast(float, u);
}

static __device__ __forceinline__ void gload_lds16(const void* g, void* l) {
    __builtin_amdgcn_global_load_lds(
        (const __attribute__((address_space(1))) unsigned int*)g,
        (__attribute__((address_space(3))) unsigned int*)l,
        16, 0, 0);
}

// ---------------------------------------------------------------------------
// Prepass 1a: x fp32 -> panA (hi) only.  [tier-2]
// ---------------------------------------------------------------------------
__global__ __launch_bounds__(256) void build_xA_panels(
    const float* __restrict__ x, unsigned short* __restrict__ panA)
{
    const int t = blockIdx.x, bm = blockIdx.y, tid = threadIdx.x;
    const size_t ubase = (size_t)(bm * 64 + t) * 2 * 8192;
#pragma unroll
    for (int u = 0; u < 8; ++u) {
        const int gid = u * 256 + tid;
        const int h = gid >> 10, rem = gid & 1023;
        const int row = rem >> 2, slot = rem & 3;
        const int kslot = slot ^ ((row >> 1) & 3);
        const float* s = x + (size_t)(bm * 256 + row) * H_DIM
                           + t * 64 + h * 32 + kslot * 8;
        f32x4 a = ((const f32x4*)s)[0], b = ((const f32x4*)s)[1];
        uint4 o;
        o.x = bf16_rn(a[0]) | (bf16_rn(a[1]) << 16);
        o.y = bf16_rn(a[2]) | (bf16_rn(a[3]) << 16);
        o.z = bf16_rn(b[0]) | (bf16_rn(b[1]) << 16);
        o.w = bf16_rn(b[2]) | (bf16_rn(b[3]) << 16);
        *(uint4*)(panA + ubase + (size_t)h * 8192 + row * 32 + slot * 8) = o;
    }
}

// ---------------------------------------------------------------------------
// Prepass 1b: x fp32 -> panA (hi) + panAl (lo).  [tier-1]
// ---------------------------------------------------------------------------
__global__ __launch_bounds__(256) void build_xA_panels_hl(
    const float* __restrict__ x, unsigned short* __restrict__ panA,
    unsigned short* __restrict__ panAl)
{
    const int t = blockIdx.x, bm = blockIdx.y, tid = threadIdx.x;
    const size_t ubase = (size_t)(bm * 64 + t) * 2 * 8192;
#pragma unroll
    for (int u = 0; u < 8; ++u) {
        const int gid = u * 256 + tid;
        const int h = gid >> 10, rem = gid & 1023;
        const int row = rem >> 2, slot = rem & 3;
        const int kslot = slot ^ ((row >> 1) & 3);
        const float* s = x + (size_t)(bm * 256 + row) * H_DIM
                           + t * 64 + h * 32 + kslot * 8;
        f32x4 a = ((const f32x4*)s)[0], b = ((const f32x4*)s)[1];
        unsigned int hb[8], lb[8];
        float v[8] = {a[0], a[1], a[2], a[3], b[0], b[1], b[2], b[3]};
#pragma unroll
        for (int q = 0; q < 8; ++q) {
            hb[q] = bf16_rn(v[q]);
            lb[q] = bf16_rn(v[q] - bf16f(hb[q]));
        }
        uint4 oh, ol;
        oh.x = hb[0] | (hb[1] << 16); oh.y = hb[2] | (hb[3] << 16);
        oh.z = hb[4] | (hb[5] << 16); oh.w = hb[6] | (hb[7] << 16);
        ol.x = lb[0] | (lb[1] << 16); ol.y = lb[2] | (lb[3] << 16);
        ol.z = lb[4] | (lb[5] << 16); ol.w = lb[6] | (lb[7] << 16);
        const size_t idx = ubase + (size_t)h * 8192 + row * 32 + slot * 8;
        *(uint4*)(panA + idx)  = oh;
        *(uint4*)(panAl + idx) = ol;
    }
}

// ---------------------------------------------------------------------------
// Prepass 2: We1[e][k][d] fp32 -> panB[nbG(64)][TT(128)]{16KB unit}.
// ---------------------------------------------------------------------------
__global__ __launch_bounds__(256) void build_w1B_panels(
    const float* __restrict__ We1, unsigned short* __restrict__ panB)
{
    __shared__ unsigned short tile[64][72];
    const int dblk = blockIdx.x, t = blockIdx.y, e = blockIdx.z;
    const int tid = threadIdx.x;
    {
        const int kr = tid >> 2, c0 = (tid & 3) * 16;
        const float* s = We1 + ((size_t)e * H_DIM + t * 64 + kr) * H2_DIM
                             + dblk * 64 + c0;
#pragma unroll
        for (int q = 0; q < 4; ++q) {
            f32x4 v = ((const f32x4*)s)[q];
            tile[kr][c0 + q * 4 + 0] = (unsigned short)bf16_rn(v[0]);
            tile[kr][c0 + q * 4 + 1] = (unsigned short)bf16_rn(v[1]);
            tile[kr][c0 + q * 4 + 2] = (unsigned short)bf16_rn(v[2]);
            tile[kr][c0 + q * 4 + 3] = (unsigned short)bf16_rn(v[3]);
        }
    }
    __syncthreads();
    const int nbG = e * 8 + (dblk >> 2);
    const int col = tid >> 2, slot = tid & 3;
    const int colg = (dblk & 3) * 64 + col;
    const int kslot = slot ^ ((colg >> 1) & 3);
#pragma unroll
    for (int hh = 0; hh < 2; ++hh) {
        const int kl = hh * 32 + kslot * 8;
        uint4 o;
        o.x = (unsigned int)tile[kl + 0][col] | ((unsigned int)tile[kl + 1][col] << 16);
        o.y = (unsigned int)tile[kl + 2][col] | ((unsigned int)tile[kl + 3][col] << 16);
        o.z = (unsigned int)tile[kl + 4][col] | ((unsigned int)tile[kl + 5][col] << 16);
        o.w = (unsigned int)tile[kl + 6][col] | ((unsigned int)tile[kl + 7][col] << 16);
        *(uint4*)(panB + (((size_t)nbG * 64 + t) * 2 + hh) * 8192
                        + colg * 32 + slot * 8) = o;
    }
}

// ---------------------------------------------------------------------------
// Prepass 3: Wg1 -> panBgh/panBgl hi/lo panels (gate).
// ---------------------------------------------------------------------------
__global__ __launch_bounds__(256) void build_wg1_panels(
    const float* __restrict__ Wg1, unsigned short* __restrict__ panBgh,
    unsigned short* __restrict__ panBgl)
{
    __shared__ unsigned short tileH[64][72];
    __shared__ unsigned short tileL[64][72];
    const int dblk = blockIdx.x, t = blockIdx.y;
    const int tid = threadIdx.x;
    {
        const int kr = tid >> 2, c0 = (tid & 3) * 16;
        const float* s = Wg1 + ((size_t)t * 64 + kr) * H2_DIM + dblk * 64 + c0;
#pragma unroll
        for (int q = 0; q < 4; ++q) {
            f32x4 v = ((const f32x4*)s)[q];
#pragma unroll
            for (int j = 0; j < 4; ++j) {
                const unsigned int hb = bf16_rn(v[j]);
                tileH[kr][c0 + q * 4 + j] = (unsigned short)hb;
                tileL[kr][c0 + q * 4 + j] =
                    (unsigned short)bf16_rn(v[j] - bf16f(hb));
            }
        }
    }
    __syncthreads();
    const int nbG = dblk >> 1;
    const int col = tid >> 2, slot = tid & 3;
    const int colg = (dblk & 1) * 64 + col;
    const int kslot = slot ^ ((colg >> 1) & 3);
#pragma unroll
    for (int hh = 0; hh < 2; ++hh) {
        const int kl = hh * 32 + kslot * 8;
        uint4 oh, ol;
        oh.x = (unsigned int)tileH[kl + 0][col] | ((unsigned int)tileH[kl + 1][col] << 16);
        oh.y = (unsigned int)tileH[kl + 2][col] | ((unsigned int)tileH[kl + 3][col] << 16);
        oh.z = (unsigned int)tileH[kl + 4][col] | ((unsigned int)tileH[kl + 5][col] << 16);
        oh.w = (unsigned int)tileH[kl + 6][col] | ((unsigned int)tileH[kl + 7][col] << 16);
        ol.x = (unsigned int)tileL[kl + 0][col] | ((unsigned int)tileL[kl + 1][col] << 16);
        ol.y = (unsigned int)tileL[kl + 2][col] | ((unsigned int)tileL[kl + 3][col] << 16);
        ol.z = (unsigned int)tileL[kl + 4][col] | ((unsigned int)tileL[kl + 5][col] << 16);
        ol.w = (unsigned int)tileL[kl + 6][col] | ((unsigned int)tileL[kl + 7][col] << 16);
        const size_t idx = (((size_t)nbG * 64 + t) * 2 + hh) * 4096
                         + colg * 32 + slot * 8;
        *(uint4*)(panBgh + idx) = oh;
        *(uint4*)(panBgl + idx) = ol;
    }
}

// ---------------------------------------------------------------------------
// Gate GEMM (panel-fed, single-buffer) — R16 verified (688us, 3 blocks/CU).
// ---------------------------------------------------------------------------
__global__ __launch_bounds__(256, 3) void moe_gate_panel(
    const unsigned short* __restrict__ panA, const unsigned short* __restrict__ panAl,
    const unsigned short* __restrict__ panBgh, const unsigned short* __restrict__ panBgl,
    const float* __restrict__ bg1, const float* __restrict__ Wg2,
    float* __restrict__ gpart)
{
    __shared__ short lAh[4096], lAl[4096];
    __shared__ short lBh[4096], lBl[4096];
    __shared__ float lW2[128 * 8];
    __shared__ float gred[2][128][8];

    const int tid  = threadIdx.x;
    const int lane = tid & 63;
    const int wv   = tid >> 6;
    const int wm   = wv >> 1;
    const int wn   = wv & 1;
    const int nb = blockIdx.x;
    const int bm = blockIdx.y;
    const int dbase = nb * 128;

    const char* AhB = (const char*)panA  + ((size_t)(bm >> 1) << 21)
                                         + ((size_t)(bm & 1) << 13);
    const char* AlB = (const char*)panAl + ((size_t)(bm >> 1) << 21)
                                         + ((size_t)(bm & 1) << 13);
    const char* BhB = (const char*)panBgh + ((size_t)nb << 20);
    const char* BlB = (const char*)panBgl + ((size_t)nb << 20);

    {
        const f32x4* s = reinterpret_cast<const f32x4*>(Wg2 + (size_t)dbase * 8);
        reinterpret_cast<f32x4*>(lW2)[tid] = s[tid];
    }

    const int rA = wm * 64 + (lane & 15);
    const int offA = rA * 64 + ((((lane >> 4)) ^ ((rA >> 1) & 3)) << 4);
    const int rB = wn * 64 + (lane & 15);
    const int offB = rB * 64 + ((((lane >> 4)) ^ ((rB >> 1) & 3)) << 4);

    f32x4 acc[4][4];
#pragma unroll
    for (int i = 0; i < 4; ++i)
#pragma unroll
        for (int j = 0; j < 4; ++j) acc[i][j] = (f32x4){0.f, 0.f, 0.f, 0.f};

#define GRD8(BASE, OFF) \
    (*reinterpret_cast<const short8*>(reinterpret_cast<const char*>(BASE) + (OFF)))

    for (int t = 0; t < 128; ++t) {
        __syncthreads();
        {
            const char* ua = AhB + ((size_t)t << 14);
            gload_lds16(ua + tid * 16,        (char*)lAh + wv * 1024);
            gload_lds16(ua + 4096 + tid * 16, (char*)lAh + 4096 + wv * 1024);
            const char* ul = AlB + ((size_t)t << 14);
            gload_lds16(ul + tid * 16,        (char*)lAl + wv * 1024);
            gload_lds16(ul + 4096 + tid * 16, (char*)lAl + 4096 + wv * 1024);
            const char* ub = BhB + ((size_t)t << 13);
            gload_lds16(ub + tid * 16,        (char*)lBh + wv * 1024);
            gload_lds16(ub + 4096 + tid * 16, (char*)lBh + 4096 + wv * 1024);
            const char* vb = BlB + ((size_t)t << 13);
            gload_lds16(vb + tid * 16,        (char*)lBl + wv * 1024);
            gload_lds16(vb + 4096 + tid * 16, (char*)lBl + 4096 + wv * 1024);
        }
        __syncthreads();

        short8 ah[4], al[4], bh[4], bl[4];
#pragma unroll
        for (int i = 0; i < 4; ++i) {
            ah[i] = GRD8(lAh, offA + i * 1024);
            al[i] = GRD8(lAl, offA + i * 1024);
        }
#pragma unroll
        for (int n = 0; n < 4; ++n) {
            bh[n] = GRD8(lBh, offB + n * 1024);
            bl[n] = GRD8(lBl, offB + n * 1024);
        }
        __builtin_amdgcn_s_setprio(1);
#pragma unroll
        for (int i = 0; i < 4; ++i)
#pragma unroll
            for (int n = 0; n < 4; ++n) {
                acc[i][n] = __builtin_amdgcn_mfma_f32_16x16x32_bf16(ah[i], bh[n], acc[i][n], 0, 0, 0);
                acc[i][n] = __builtin_amdgcn_mfma_f32_16x16x32_bf16(ah[i], bl[n], acc[i][n], 0, 0, 0);
                acc[i][n] = __builtin_amdgcn_mfma_f32_16x16x32_bf16(al[i], bh[n], acc[i][n], 0, 0, 0);
            }
        __builtin_amdgcn_s_setprio(0);
    }
#undef GRD8

    const int c = lane & 15, g = lane >> 4;
    float bgv[4];
#pragma unroll
    for (int ni = 0; ni < 4; ++ni) bgv[ni] = bg1[dbase + wn * 64 + ni * 16 + c];
#pragma unroll
    for (int mi = 0; mi < 4; ++mi) {
#pragma unroll
        for (int r = 0; r < 4; ++r) {
            float gv[4];
#pragma unroll
            for (int ni = 0; ni < 4; ++ni)
                gv[ni] = fmaxf(acc[mi][ni][r] + bgv[ni], 0.f);
#pragma unroll
            for (int e8 = 0; e8 < 8; ++e8) {
                float tsum = 0.f;
#pragma unroll
                for (int ni = 0; ni < 4; ++ni)
                    tsum = fmaf(gv[ni], lW2[(wn * 64 + ni * 16 + c) * 8 + e8], tsum);
                tsum += __shfl_xor(tsum, 1);
                tsum += __shfl_xor(tsum, 2);
                tsum += __shfl_xor(tsum, 4);
                tsum += __shfl_xor(tsum, 8);
                if (c == e8) gred[wn][wm * 64 + mi * 16 + g * 4 + r][e8] = tsum;
            }
        }
    }
    __syncthreads();
    {
        const int row = tid & 127;
        const int ebase = (tid >> 7) * 4;
        const int b = bm * 128 + row;
#pragma unroll
        for (int i = 0; i < 4; ++i) {
            const int e8 = ebase + i;
            gpart[(size_t)b * 128 + nb * 8 + e8] =
                gred[0][row][e8] + gred[1][row][e8];
        }
    }
}

// ---------------------------------------------------------------------------
// Routing: zero counters; logits+top2+list build; tile table.
// ---------------------------------------------------------------------------
__global__ void route_zero(int* __restrict__ cnt) {
    if (threadIdx.x < E_DIM) cnt[threadIdx.x] = 0;
}

__global__ __launch_bounds__(256) void moe_logits_topk(
    const float* __restrict__ gpart, const float* __restrict__ bg2,
    int* __restrict__ sel, float* __restrict__ w2f,
    int* __restrict__ cnt, int* __restrict__ tokenlist)
{
    const int b = blockIdx.x * 256 + threadIdx.x;
    float logit[8];
#pragma unroll
    for (int e = 0; e < 8; ++e) logit[e] = bg2[e];
    const float* gp = gpart + (size_t)b * 128;
#pragma unroll
    for (int cN = 0; cN < 16; ++cN)
#pragma unroll
        for (int e = 0; e < 8; ++e) logit[e] += gp[cN * 8 + e];

    int i1 = 0; float m1 = logit[0];
#pragma unroll
    for (int e = 1; e < 8; ++e) if (logit[e] > m1) { m1 = logit[e]; i1 = e; }
    int i2 = -1; float m2 = -3.4e38f;
#pragma unroll
    for (int e = 0; e < 8; ++e) if (e != i1 && logit[e] > m2) { m2 = logit[e]; i2 = e; }

    sel[b] = i1 | (i2 << 8);
    w2f[b] = expf(m2 - m1);
    const int p1 = atomicAdd(&cnt[i1], 1);
    tokenlist[i1 * B_DIM + p1] = (b << 1);
    const int p2 = atomicAdd(&cnt[i2], 1);
    tokenlist[i2 * B_DIM + p2] = (b << 1) | 1;
}

__global__ void moe_tiletab(
    const int* __restrict__ cnt, int* __restrict__ tileE,
    int* __restrict__ tileB, int* __restrict__ nTiles)
{
    if (threadIdx.x == 0) {
        int tot = 0;
        for (int e = 0; e < E_DIM; ++e) {
            const int nt = (cnt[e] + 127) >> 7;
            for (int j = 0; j < nt; ++j) { tileE[tot] = e; tileB[tot] = j; ++tot; }
        }
        *nTiles = tot;
    }
}

// ---------------------------------------------------------------------------
// Sparse expert GEMM (R16 verified): R10 3-buffer pipeline, gathered A,
// chunk-fastest grid (8 chunk-siblings share A via L3).
// Output esel[token][slot(2)][chunk(8)].
// ---------------------------------------------------------------------------
__global__ __launch_bounds__(512, 4) void moe_expert_sparse(
    const unsigned short* __restrict__ panA, const unsigned short* __restrict__ panB,
    const float* __restrict__ be1, const float* __restrict__ We2,
    const int* __restrict__ tileE, const int* __restrict__ tileB,
    const int* __restrict__ nTiles, const int* __restrict__ cnt,
    const int* __restrict__ tokenlist, float* __restrict__ esel)
{
    __shared__ short lA[3][4096];
    __shared__ short lB[3][8192];
    __shared__ float red[4][128];
    __shared__ int   tokbuf[128];

    const int tix = blockIdx.y;           // tile index (chunk-fastest grid)
    if (tix >= *nTiles) return;           // uniform exit before any barrier
    const int chunk = blockIdx.x;

    const int tid  = threadIdx.x;
    const int lane = tid & 63;
    const int wv   = tid >> 6;
    const int wm   = wv >> 2;
    const int wn   = wv & 3;

    const int e  = tileE[tix];
    const int tb = tileB[tix];
    const int ce = cnt[e];
    const int nb = e * 8 + chunk;
    const int dbase = chunk * 256;

    if (tid < 128) {
        const int gi = tb * 128 + tid;
        tokbuf[tid] = (gi < ce) ? tokenlist[e * B_DIM + gi] : -1;
    }
    __syncthreads();

    // per-thread gathered A source (swizzle corrected per token row)
    const int rawT = tokbuf[tid >> 2];
    const int tokv = ((rawT < 0) ? tokbuf[0] : rawT) >> 1;
    const int trow = tokv & 255;
    const int lr = tid >> 2, ls = tid & 3;
    const int sslot = ls ^ ((lr >> 1) & 3) ^ ((trow >> 1) & 3);
    const char* Asrc = (const char*)panA + ((size_t)(tokv >> 8) << 21)
                     + trow * 64 + sslot * 16;
    const char* Bbase = (const char*)panB + ((size_t)nb << 21);

#define STAGE(TT, CC) do {                                                     \
    gload_lds16(Asrc + ((size_t)(TT) << 14), (char*)&lA[CC][0] + wv * 1024);   \
    const char* ub_ = Bbase + ((size_t)(TT) << 14);                            \
    gload_lds16(ub_ + tid * 16, (char*)&lB[CC][0] + wv * 1024);                \
    gload_lds16(ub_ + 8192 + tid * 16, (char*)&lB[CC][0] + 8192 + wv * 1024);  \
} while (0)

#define RD8(BASE, OFF) \
    (*reinterpret_cast<const short8*>(reinterpret_cast<const char*>(BASE) + (OFF)))

    const int rA = wm * 64 + (lane & 15);
    const int offA = rA * 64 + ((((lane >> 4)) ^ ((rA >> 1) & 3)) << 4);
    const int rB = wn * 64 + (lane & 15);
    const int offB = rB * 64 + ((((lane >> 4)) ^ ((rB >> 1) & 3)) << 4);

    f32x4 acc[4][4];
#pragma unroll
    for (int i = 0; i < 4; ++i)
#pragma unroll
        for (int j = 0; j < 4; ++j) acc[i][j] = (f32x4){0.f, 0.f, 0.f, 0.f};

    STAGE(0, 0);
    STAGE(1, 1);
    asm volatile("s_waitcnt vmcnt(3)");
    __builtin_amdgcn_s_barrier();

#define ITER(CUR, NXT, TN) do {                                                \
    STAGE(TN, NXT);                                                            \
    short8 af_[4], bf_[4];                                                     \
    _Pragma("unroll")                                                          \
    for (int i = 0; i < 4; ++i) af_[i] = RD8(&lA[CUR][0], offA + i * 1024);    \
    _Pragma("unroll")                                                          \
    for (int n = 0; n < 4; ++n) bf_[n] = RD8(&lB[CUR][0], offB + n * 1024);    \
    __builtin_amdgcn_s_setprio(1);                                             \
    _Pragma("unroll")                                                          \
    for (int i = 0; i < 4; ++i)                                                \
        _Pragma("unroll")                                                      \
        for (int n = 0; n < 4; ++n)                                            \
            acc[i][n] = __builtin_amdgcn_mfma_f32_16x16x32_bf16(af_[i], bf_[n], acc[i][n], 0, 0, 0); \
    __builtin_amdgcn_s_setprio(0);                                             \
    asm volatile("s_waitcnt vmcnt(3)");                                        \
    __builtin_amdgcn_s_barrier();                                              \
} while (0)

    for (int t = 0; t < 126; t += 3) {
        ITER(0, 2, t + 2);
        ITER(1, 0, t + 3);
        ITER(2, 1, t + 4);
    }
    ITER(0, 2, 127);
    ITER(1, 0, 127);
    asm volatile("s_waitcnt vmcnt(0)");
#undef ITER
#undef STAGE

    const int cc = lane & 15, g = lane >> 4;
    float w2v[4], b1v[4];
#pragma unroll
    for (int ni = 0; ni < 4; ++ni) {
        const int d = dbase + wn * 64 + ni * 16 + cc;
        b1v[ni] = be1[e * H2_DIM + d];
        w2v[ni] = We2[e * H2_DIM + d];
    }
#pragma unroll
    for (int mi = 0; mi < 4; ++mi) {
#pragma unroll
        for (int r = 0; r < 4; ++r) {
            float s = 0.f;
#pragma unroll
            for (int ni = 0; ni < 4; ++ni) {
                float v = acc[mi][ni][r] + b1v[ni];
                v = fmaxf(v, 0.f);
                s = fmaf(v, w2v[ni], s);
            }
            s += __shfl_xor(s, 1);
            s += __shfl_xor(s, 2);
            s += __shfl_xor(s, 4);
            s += __shfl_xor(s, 8);
            if (cc == 0) red[wn][wm * 64 + mi * 16 + g * 4 + r] = s;
        }
    }
    __syncthreads();
    if (tid < 128) {
        const int r2 = tokbuf[tid];
        if (r2 >= 0) {
            const int tk = r2 >> 1, sl = r2 & 1;
            esel[(size_t)tk * 16 + sl * 8 + chunk] =
                red[0][tid] + red[1][tid] + red[2][tid] + red[3][tid];
        }
    }
}

// ---------------------------------------------------------------------------
// Sparse finalize: combine the two selected experts.
// ---------------------------------------------------------------------------
__global__ __launch_bounds__(256) void moe_finalize_sparse(
    const float* __restrict__ esel, const int* __restrict__ sel,
    const float* __restrict__ w2f, const float* __restrict__ be2,
    float* __restrict__ out)
{
    const int b = blockIdx.x * 256 + threadIdx.x;
    const int s = sel[b];
    const int i1 = s & 255, i2 = (s >> 8) & 255;
    const float w2 = w2f[b];
    const float* ep = esel + (size_t)b * 16;
    float eo1 = be2[i1], eo2 = be2[i2];
#pragma unroll
    for (int c = 0; c < 8; ++c) eo1 += ep[c];
#pragma unroll
    for (int c = 0; c < 8; ++c) eo2 += ep[8 + c];
    out[b] = (eo1 + w2 * eo2) / (1.f + w2);
}

// ---------------------------------------------------------------------------
// Dense expert GEMM (R10 verbatim) — tier-2.
// ---------------------------------------------------------------------------
__global__ __launch_bounds__(512, 4) void moe_expert_gemm_128(
    const unsigned short* __restrict__ panA, const unsigned short* __restrict__ panB,
    const float* __restrict__ be1, const float* __restrict__ We2,
    float* __restrict__ epart)
{
    __shared__ short lA[3][4096];
    __shared__ short lB[3][8192];
    __shared__ float red[4][128];

    const int tid  = threadIdx.x;
    const int lane = tid & 63;
    const int wv   = tid >> 6;
    const int wm   = wv >> 2;
    const int wn   = wv & 3;

    const int lin = blockIdx.x;
    const int sb  = lin >> 8, i5 = lin & 255;
    const int sbm = sb & 7, snb = sb >> 3;
    const int xcd = i5 & 7, j5 = i5 >> 3;
    const int bm  = sbm * 16 + (xcd & 1) * 8 + (j5 & 7);
    const int nb  = snb * 16 + (xcd >> 1) * 4 + (j5 >> 3);
    const int e = nb >> 3, chunk = nb & 7;
    const int dbase = chunk * 256;

    const char* Abase = (const char*)panA + ((size_t)(bm >> 1) << 21)
                                          + ((size_t)(bm & 1) << 13);
    const char* Bbase = (const char*)panB + ((size_t)nb << 21);

#define STAGE(TT, CC) do {                                                     \
    const char* ua_ = Abase + ((size_t)(TT) << 14);                            \
    gload_lds16(ua_ + tid * 16, (char*)&lA[CC][0] + wv * 1024);                \
    const char* ub_ = Bbase + ((size_t)(TT) << 14);                            \
    gload_lds16(ub_ + tid * 16, (char*)&lB[CC][0] + wv * 1024);                \
    gload_lds16(ub_ + 8192 + tid * 16, (char*)&lB[CC][0] + 8192 + wv * 1024);  \
} while (0)

#define RD8(BASE, OFF) \
    (*reinterpret_cast<const short8*>(reinterpret_cast<const char*>(BASE) + (OFF)))

    const int rA = wm * 64 + (lane & 15);
    const int offA = rA * 64 + ((((lane >> 4)) ^ ((rA >> 1) & 3)) << 4);
    const int rB = wn * 64 + (lane & 15);
    const int offB = rB * 64 + ((((lane >> 4)) ^ ((rB >> 1) & 3)) << 4);

    f32x4 acc[4][4];
#pragma unroll
    for (int i = 0; i < 4; ++i)
#pragma unroll
        for (int j = 0; j < 4; ++j) acc[i][j] = (f32x4){0.f, 0.f, 0.f, 0.f};

    STAGE(0, 0);
    STAGE(1, 1);
    asm volatile("s_waitcnt vmcnt(3)");
    __builtin_amdgcn_s_barrier();

#define ITER(CUR, NXT, TN) do {                                                \
    STAGE(TN, NXT);                                                            \
    short8 af_[4], bf_[4];                                                     \
    _Pragma("unroll")                                                          \
    for (int i = 0; i < 4; ++i) af_[i] = RD8(&lA[CUR][0], offA + i * 1024);    \
    _Pragma("unroll")                                                          \
    for (int n = 0; n < 4; ++n) bf_[n] = RD8(&lB[CUR][0], offB + n * 1024);    \
    __builtin_amdgcn_s_setprio(1);                                             \
    _Pragma("unroll")                                                          \
    for (int i = 0; i < 4; ++i)                                                \
        _Pragma("unroll")                                                      \
        for (int n = 0; n < 4; ++n)                                            \
            acc[i][n] = __builtin_amdgcn_mfma_f32_16x16x32_bf16(af_[i], bf_[n], acc[i][n], 0, 0, 0); \
    __builtin_amdgcn_s_setprio(0);                                             \
    asm volatile("s_waitcnt vmcnt(3)");                                        \
    __builtin_amdgcn_s_barrier();                                              \
} while (0)

    for (int t = 0; t < 126; t += 3) {
        ITER(0, 2, t + 2);
        ITER(1, 0, t + 3);
        ITER(2, 1, t + 4);
    }
    ITER(0, 2, 127);
    ITER(1, 0, 127);
    asm volatile("s_waitcnt vmcnt(0)");
#undef ITER
#undef STAGE

    const int cc = lane & 15, g = lane >> 4;
    float w2v[4], b1v[4];
#pragma unroll
    for (int ni = 0; ni < 4; ++ni) {
        const int d = dbase + wn * 64 + ni * 16 + cc;
        b1v[ni] = be1[e * H2_DIM + d];
        w2v[ni] = We2[e * H2_DIM + d];
    }
#pragma unroll
    for (int mi = 0; mi < 4; ++mi) {
#pragma unroll
        for (int r = 0; r < 4; ++r) {
            float s = 0.f;
#pragma unroll
            for (int ni = 0; ni < 4; ++ni) {
                float v = acc[mi][ni][r] + b1v[ni];
                v = fmaxf(v, 0.f);
                s = fmaf(v, w2v[ni], s);
            }
            s += __shfl_xor(s, 1);
            s += __shfl_xor(s, 2);
            s += __shfl_xor(s, 4);
            s += __shfl_xor(s, 8);
            if (cc == 0) red[wn][wm * 64 + mi * 16 + g * 4 + r] = s;
        }
    }
    __syncthreads();
    if (tid < 128) {
        const int b = bm * 128 + tid;
        epart[((size_t)b * E_DIM + e) * 8 + chunk] =
            red[0][tid] + red[1][tid] + red[2][tid] + red[3][tid];
    }
}

// ---------------------------------------------------------------------------
// Fallback gate GEMM (fp32 in-kernel split) — round-1 verified. [tier-2/3]
// ---------------------------------------------------------------------------
__global__ __launch_bounds__(256, 2) void moe_gate_gemm(
    const float* __restrict__ x, const float* __restrict__ Wg1,
    const float* __restrict__ bg1, const float* __restrict__ Wg2,
    float* __restrict__ gpart)
{
    __shared__ short lAh[128 * 64], lAl[128 * 64];
    __shared__ short lBh[128 * 64], lBl[128 * 64];
    __shared__ float lW2[128 * 8];
    __shared__ float gred[2][128][8];

    const int tid  = threadIdx.x;
    const int lane = tid & 63;
    const int wm = (tid >> 6) >> 1, wn = (tid >> 6) & 1;
    const int nb = blockIdx.x, bm = blockIdx.y;
    const int dbase = nb * 128;

    const float* Asrc = x + (size_t)bm * 128 * H_DIM;
    const float* Bsrc = Wg1 + dbase;

    {
        const f32x4* s = reinterpret_cast<const f32x4*>(Wg2 + (size_t)dbase * 8);
        reinterpret_cast<f32x4*>(lW2)[tid] = s[tid];
    }

    f32x4 acc[4][4];
#pragma unroll
    for (int i = 0; i < 4; ++i)
#pragma unroll
        for (int j = 0; j < 4; ++j) acc[i][j] = (f32x4){0.f, 0.f, 0.f, 0.f};

    const int arow0 = tid >> 4, af4 = tid & 15;
    const int bn = tid & 127, bkc0 = tid >> 7;

    for (int k0 = 0; k0 < H_DIM; k0 += 64) {
        __syncthreads();
#pragma unroll
        for (int j = 0; j < 8; ++j) {
            const int row = arow0 + j * 16;
            const float* p = Asrc + (size_t)row * H_DIM + k0 + af4 * 4;
            float a[4] = {p[0], p[1], p[2], p[3]};
            unsigned int hb[4], lb[4];
#pragma unroll
            for (int q = 0; q < 4; ++q) {
                hb[q] = bf16_rn(a[q]);
                lb[q] = bf16_rn(a[q] - bf16f(hb[q]));
            }
            const int byte = row * 128 + ((af4 * 8) ^ ((row & 7) << 4));
            *reinterpret_cast<uint2*>(reinterpret_cast<char*>(lAh) + byte) =
                make_uint2(hb[0] | (hb[1] << 16), hb[2] | (hb[3] << 16));
            *reinterpret_cast<uint2*>(reinterpret_cast<char*>(lAl) + byte) =
                make_uint2(lb[0] | (lb[1] << 16), lb[2] | (lb[3] << 16));
        }
#pragma unroll
        for (int j = 0; j < 4; ++j) {
            const int kc = bkc0 + 2 * j;
            const float* p = Bsrc + (size_t)(k0 + kc * 8) * H2_DIM + bn;
            unsigned int hb[8], lb[8];
#pragma unroll
            for (int q = 0; q < 8; ++q) {
                float v = p[(size_t)q * H2_DIM];
                hb[q] = bf16_rn(v);
                lb[q] = bf16_rn(v - bf16f(hb[q]));
            }
            const int byte = bn * 128 + ((kc * 16) ^ ((bn & 7) << 4));
            *reinterpret_cast<uint4*>(reinterpret_cast<char*>(lBh) + byte) =
                make_uint4(hb[0] | (hb[1] << 16), hb[2] | (hb[3] << 16),
                           hb[4] | (hb[5] << 16), hb[6] | (hb[7] << 16));
            *reinterpret_cast<uint4*>(reinterpret_cast<char*>(lBl) + byte) =
                make_uint4(lb[0] | (lb[1] << 16), lb[2] | (lb[3] << 16),
                           lb[4] | (lb[5] << 16), lb[6] | (lb[7] << 16));
        }
        __syncthreads();
#pragma unroll
        for (int kk = 0; kk < 2; ++kk) {
            const int kbyte = kk * 64 + ((lane >> 4) << 4);
            short8 ah[4], al[4], bh[4], bl[4];
#pragma unroll
            for (int mi = 0; mi < 4; ++mi) {
                const int r = wm * 64 + mi * 16 + (lane & 15);
                const int off = r * 128 + (kbyte ^ ((r & 7) << 4));
                ah[mi] = *reinterpret_cast<const short8*>(reinterpret_cast<const char*>(lAh) + off);
                al[mi] = *reinterpret_cast<const short8*>(reinterpret_cast<const char*>(lAl) + off);
            }
#pragma unroll
            for (int ni = 0; ni < 4; ++ni) {
                const int r = wn * 64 + ni * 16 + (lane & 15);
                const int off = r * 128 + (kbyte ^ ((r & 7) << 4));
                bh[ni] = *reinterpret_cast<const short8*>(reinterpret_cast<const char*>(lBh) + off);
                bl[ni] = *reinterpret_cast<const short8*>(reinterpret_cast<const char*>(lBl) + off);
            }
#pragma unroll
            for (int mi = 0; mi < 4; ++mi)
#pragma unroll
                for (int ni = 0; ni < 4; ++ni) {
                    acc[mi][ni] = __builtin_amdgcn_mfma_f32_16x16x32_bf16(ah[mi], bh[ni], acc[mi][ni], 0, 0, 0);
                    acc[mi][ni] = __builtin_amdgcn_mfma_f32_16x16x32_bf16(ah[mi], bl[ni], acc[mi][ni], 0, 0, 0);
                    acc[mi][ni] = __builtin_amdgcn_mfma_f32_16x16x32_bf16(al[mi], bh[ni], acc[mi][ni], 0, 0, 0);
                }
        }
    }

    const int c = lane & 15, g = lane >> 4;
    float bgv[4];
#pragma unroll
    for (int ni = 0; ni < 4; ++ni) bgv[ni] = bg1[dbase + wn * 64 + ni * 16 + c];
#pragma unroll
    for (int mi = 0; mi < 4; ++mi) {
#pragma unroll
        for (int r = 0; r < 4; ++r) {
            float gv[4];
#pragma unroll
            for (int ni = 0; ni < 4; ++ni)
                gv[ni] = fmaxf(acc[mi][ni][r] + bgv[ni], 0.f);
#pragma unroll
            for (int e8 = 0; e8 < 8; ++e8) {
                float t = 0.f;
#pragma unroll
                for (int ni = 0; ni < 4; ++ni)
                    t = fmaf(gv[ni], lW2[(wn * 64 + ni * 16 + c) * 8 + e8], t);
                t += __shfl_xor(t, 1);
                t += __shfl_xor(t, 2);
                t += __shfl_xor(t, 4);
                t += __shfl_xor(t, 8);
                if (c == e8) gred[wn][wm * 64 + mi * 16 + g * 4 + r][e8] = t;
            }
        }
    }
    __syncthreads();
    {
        const int row = tid & 127;
        const int ebase = (tid >> 7) * 4;
        const int b = bm * 128 + row;
#pragma unroll
        for (int i = 0; i < 4; ++i) {
            const int e8 = ebase + i;
            gpart[(size_t)b * 128 + nb * 8 + e8] = gred[0][row][e8] + gred[1][row][e8];
        }
    }
}

// ---------------------------------------------------------------------------
// Fallback expert GEMM (fp32 in-kernel conversion) — round-1 verified. [tier-3]
// ---------------------------------------------------------------------------
__global__ __launch_bounds__(256, 2) void moe_expert_gemm(
    const float* __restrict__ x, const float* __restrict__ We1,
    const float* __restrict__ be1, const float* __restrict__ We2,
    float* __restrict__ epart)
{
    __shared__ short lA[128 * 64];
    __shared__ short lB[128 * 64];
    __shared__ float red[2][128];

    const int tid  = threadIdx.x;
    const int lane = tid & 63;
    const int wm   = (tid >> 6) >> 1;
    const int wn   = (tid >> 6) & 1;
    const int nb = blockIdx.x, bm = blockIdx.y;
    const int e = nb >> 4, chunk = nb & 15;
    const int dbase = chunk * 128;

    const float* Asrc = x + (size_t)bm * 128 * H_DIM;
    const float* Bsrc = We1 + (size_t)e * H_DIM * H2_DIM + dbase;

    f32x4 acc[4][4];
#pragma unroll
    for (int i = 0; i < 4; ++i)
#pragma unroll
        for (int j = 0; j < 4; ++j) acc[i][j] = (f32x4){0.f, 0.f, 0.f, 0.f};

    const int arow0 = tid >> 4, af4 = tid & 15;
    const int bn = tid & 127, bkc0 = tid >> 7;

    for (int k0 = 0; k0 < H_DIM; k0 += 64) {
        __syncthreads();
#pragma unroll
        for (int j = 0; j < 8; ++j) {
            const int row = arow0 + j * 16;
            const float* p = Asrc + (size_t)row * H_DIM + k0 + af4 * 4;
            float a0 = p[0], a1 = p[1], a2 = p[2], a3 = p[3];
            uint2 wv2;
            wv2.x = bf16_rn(a0) | (bf16_rn(a1) << 16);
            wv2.y = bf16_rn(a2) | (bf16_rn(a3) << 16);
            const int byte = row * 128 + ((af4 * 8) ^ ((row & 7) << 4));
            *reinterpret_cast<uint2*>(reinterpret_cast<char*>(lA) + byte) = wv2;
        }
#pragma unroll
        for (int j = 0; j < 4; ++j) {
            const int kc = bkc0 + 2 * j;
            const float* p = Bsrc + (size_t)(k0 + kc * 8) * H2_DIM + bn;
            uint4 wv4;
            wv4.x = bf16_rn(p[0])          | (bf16_rn(p[H2_DIM])     << 16);
            wv4.y = bf16_rn(p[2 * H2_DIM]) | (bf16_rn(p[3 * H2_DIM]) << 16);
            wv4.z = bf16_rn(p[4 * H2_DIM]) | (bf16_rn(p[5 * H2_DIM]) << 16);
            wv4.w = bf16_rn(p[6 * H2_DIM]) | (bf16_rn(p[7 * H2_DIM]) << 16);
            const int byte = bn * 128 + ((kc * 16) ^ ((bn & 7) << 4));
            *reinterpret_cast<uint4*>(reinterpret_cast<char*>(lB) + byte) = wv4;
        }
        __syncthreads();
#pragma unroll
        for (int kk = 0; kk < 2; ++kk) {
            const int kbyte = kk * 64 + ((lane >> 4) << 4);
            short8 af[4], bfr[4];
#pragma unroll
            for (int mi = 0; mi < 4; ++mi) {
                const int r = wm * 64 + mi * 16 + (lane & 15);
                af[mi] = *reinterpret_cast<const short8*>(
                    reinterpret_cast<const char*>(lA) + r * 128 + (kbyte ^ ((r & 7) << 4)));
            }
#pragma unroll
            for (int ni = 0; ni < 4; ++ni) {
                const int r = wn * 64 + ni * 16 + (lane & 15);
                bfr[ni] = *reinterpret_cast<const short8*>(
                    reinterpret_cast<const char*>(lB) + r * 128 + (kbyte ^ ((r & 7) << 4)));
            }
#pragma unroll
            for (int mi = 0; mi < 4; ++mi)
#pragma unroll
                for (int ni = 0; ni < 4; ++ni)
                    acc[mi][ni] = __builtin_amdgcn_mfma_f32_16x16x32_bf16(
                        af[mi], bfr[ni], acc[mi][ni], 0, 0, 0);
        }
    }

    const int c = lane & 15, g = lane >> 4;
    float w2v[4], b1v[4];
#pragma unroll
    for (int ni = 0; ni < 4; ++ni) {
        const int d = dbase + wn * 64 + ni * 16 + c;
        b1v[ni] = be1[e * H2_DIM + d];
        w2v[ni] = We2[e * H2_DIM + d];
    }
#pragma unroll
    for (int mi = 0; mi < 4; ++mi) {
#pragma unroll
        for (int r = 0; r < 4; ++r) {
            float s = 0.f;
#pragma unroll
            for (int ni = 0; ni < 4; ++ni) {
                float v = acc[mi][ni][r] + b1v[ni];
                v = fmaxf(v, 0.f);
                s = fmaf(v, w2v[ni], s);
            }
            s += __shfl_xor(s, 1);
            s += __shfl_xor(s, 2);
            s += __shfl_xor(s, 4);
            s += __shfl_xor(s, 8);
            if (c == 0) red[wn][wm * 64 + mi * 16 + g * 4 + r] = s;
        }
    }
    __syncthreads();
    if (tid < 128) {
        const int b = bm * 128 + tid;
        epart[((size_t)b * E_DIM + e) * 16 + chunk] = red[0][tid] + red[1][tid];
    }
}

// ---------------------------------------------------------------------------
// Dense finalize — tiers 2/3.
// ---------------------------------------------------------------------------
template <int NC>
__global__ __launch_bounds__(256) void moe_finalize(
    const float* __restrict__ gpart, const float* __restrict__ epart,
    const float* __restrict__ bg2, const float* __restrict__ be2,
    float* __restrict__ out)
{
    const int b = blockIdx.x * 256 + threadIdx.x;
    float logit[8];
#pragma unroll
    for (int e = 0; e < 8; ++e) logit[e] = bg2[e];
    const float* gp = gpart + (size_t)b * 128;
#pragma unroll
    for (int cN = 0; cN < 16; ++cN)
#pragma unroll
        for (int e = 0; e < 8; ++e) logit[e] += gp[cN * 8 + e];

    float eo[8];
    const float* ep = epart + (size_t)b * E_DIM * NC;
#pragma unroll
    for (int e = 0; e < 8; ++e) {
        float s = be2[e];
#pragma unroll
        for (int cN = 0; cN < NC; ++cN) s += ep[e * NC + cN];
        eo[e] = s;
    }

    int i1 = 0; float m1 = logit[0];
#pragma unroll
    for (int e = 1; e < 8; ++e) if (logit[e] > m1) { m1 = logit[e]; i1 = e; }
    int i2 = -1; float m2 = -3.4e38f;
#pragma unroll
    for (int e = 0; e < 8; ++e) if (e != i1 && logit[e] > m2) { m2 = logit[e]; i2 = e; }

    const float w2 = expf(m2 - m1);
    out[b] = (eo[i1] + w2 * eo[i2]) / (1.f + w2);
}

// ---------------------------------------------------------------------------
extern "C" void kernel_launch(void* const* d_in, const int* in_sizes, int n_in,
                              void* d_out, int out_size, void* d_ws, size_t ws_size,
                              hipStream_t stream) {
    (void)in_sizes; (void)n_in; (void)out_size;
    const float* x   = (const float*)d_in[0];
    const float* We1 = (const float*)d_in[1];
    const float* be1 = (const float*)d_in[2];
    const float* We2 = (const float*)d_in[3];
    const float* be2 = (const float*)d_in[4];
    const float* Wg1 = (const float*)d_in[5];
    const float* bg1 = (const float*)d_in[6];
    const float* Wg2 = (const float*)d_in[7];
    const float* bg2 = (const float*)d_in[8];
    float* out = (float*)d_out;

    char* ws = (char*)d_ws;
    size_t off = 0;
    float* gpart = (float*)(ws + off);                  off += (size_t)B_DIM * 128 * 4;            // 8 MB
    float* epart = (float*)(ws + off);                  off += (size_t)B_DIM * 128 * 4;            // 8 MB (esel front 1MB)
    unsigned short* panA = (unsigned short*)(ws + off); off += (size_t)B_DIM * H_DIM * 2;          // 128 MB
    unsigned short* panB = (unsigned short*)(ws + off); off += (size_t)E_DIM * H2_DIM * H_DIM * 2; // 128 MB
    const size_t NEED2 = off;
    unsigned short* panAl  = (unsigned short*)(ws + off); off += (size_t)B_DIM * H_DIM * 2;        // 128 MB
    unsigned short* panBgh = (unsigned short*)(ws + off); off += (size_t)H2_DIM * H_DIM * 2;       // 16 MB
    unsigned short* panBgl = (unsigned short*)(ws + off); off += (size_t)H2_DIM * H_DIM * 2;       // 16 MB
    int*   cnt       = (int*)(ws + off);   off += 256;
    int*   nTiles    = (int*)(ws + off);   off += 256;
    int*   tileE     = (int*)(ws + off);   off += 272 * 4;
    int*   tileB     = (int*)(ws + off);   off += 272 * 4;
    int*   sel       = (int*)(ws + off);   off += (size_t)B_DIM * 4;          // 64 KB
    float* w2f       = (float*)(ws + off); off += (size_t)B_DIM * 4;          // 64 KB
    int*   tokenlist = (int*)(ws + off);   off += (size_t)E_DIM * B_DIM * 4;  // 512 KB
    const size_t NEED1 = off;
    float* esel = epart;

    if (ws_size >= NEED1) {
        build_xA_panels_hl<<<dim3(64, 64), 256, 0, stream>>>(x, panA, panAl);
        build_wg1_panels<<<dim3(32, 64), 256, 0, stream>>>(Wg1, panBgh, panBgl);
        route_zero<<<1, 64, 0, stream>>>(cnt);
        moe_gate_panel<<<dim3(16, 128), 256, 0, stream>>>(panA, panAl, panBgh, panBgl,
                                                          bg1, Wg2, gpart);
        moe_logits_topk<<<64, 256, 0, stream>>>(gpart, bg2, sel, w2f, cnt, tokenlist);
        build_w1B_panels<<<dim3(32, 64, 8), 256, 0, stream>>>(We1, panB);  // panB L3-hot
        moe_tiletab<<<1, 64, 0, stream>>>(cnt, tileE, tileB, nTiles);
        moe_expert_sparse<<<dim3(8, 264), 512, 0, stream>>>(
            panA, panB, be1, We2, tileE, tileB, nTiles, cnt, tokenlist, esel);
        moe_finalize_sparse<<<64, 256, 0, stream>>>(esel, sel, w2f, be2, out);
    } else if (ws_size >= NEED2) {
        build_xA_panels<<<dim3(64, 64), 256, 0, stream>>>(x, panA);
        build_w1B_panels<<<dim3(32, 64, 8), 256, 0, stream>>>(We1, panB);
        moe_expert_gemm_128<<<8192, 512, 0, stream>>>(panA, panB, be1, We2, epart);
        moe_gate_gemm<<<dim3(16, 128), 256, 0, stream>>>(x, Wg1, bg1, Wg2, gpart);
        moe_finalize<8><<<64, 256, 0, stream>>>(gpart, epart, bg2, be2, out);
    } else {
        moe_expert_gemm<<<dim3(128, 128), 256, 0, stream>>>(x, We1, be1, We2, epart);
        moe_gate_gemm<<<dim3(16, 128), 256, 0, stream>>>(x, Wg1, bg1, Wg2, gpart);
        moe_finalize<16><<<64, 256, 0, stream>>>(gpart, epart, bg2, be2, out);
    }
}

// Round 20
// 1634.507 us; speedup vs baseline: 1.1245x; 1.0033x over previous
//
#include <hip/hip_runtime.h>
#include <hip/hip_bf16.h>
#include <stdint.h>

// MoE head R20 = R19 (best: 1.64ms) with a B-DIRECT pipelined gate:
//  - gate: A double-buffered through LDS (stage-ahead-1, cheap vmcnt(0) end
//    drain covers only 4 loads), B read straight from pre-swizzled panBg
//    units into registers (coalesced; issued BEFORE the A stage so the
//    compiler's B-wait is a counted vmcnt leaving A in flight). LDS 44KB ->
//    3 blocks/CU kept. Math identical to R16/R19 (3-term split).
//  - sparse expert: R16 3-buffer vmcnt(3), chunk-fastest grid (verified)
//  - launch order: build_w1B AFTER gate/topk (panB L3-hot)
// Tiers: ws>=NEED1 sparse; >=NEED2 dense R10; else R1 fallback.

#define B_DIM  16384
#define H_DIM  4096
#define H2_DIM 2048
#define E_DIM  8

typedef __attribute__((ext_vector_type(8))) short short8;
typedef __attribute__((ext_vector_type(4))) float f32x4;

static __device__ __forceinline__ unsigned int bf16_rn(float f) {
    unsigned int u = __builtin_bit_cast(unsigned int, f);
    u += 0x7FFFu + ((u >> 16) & 1u);
    return u >> 16;
}
static __device__ __forceinline__ float bf16f(unsigned int h) {
    unsigned int u = h << 16;
    return __builtin_bit_cast(float, u);
}

static __device__ __forceinline__ void gload_lds16(const void* g, void* l) {
    __builtin_amdgcn_global_load_lds(
        (const __attribute__((address_space(1))) unsigned int*)g,
        (__attribute__((address_space(3))) unsigned int*)l,
        16, 0, 0);
}

// ---------------------------------------------------------------------------
// Prepass 1a: x fp32 -> panA (hi) only.  [tier-2]
// ---------------------------------------------------------------------------
__global__ __launch_bounds__(256) void build_xA_panels(
    const float* __restrict__ x, unsigned short* __restrict__ panA)
{
    const int t = blockIdx.x, bm = blockIdx.y, tid = threadIdx.x;
    const size_t ubase = (size_t)(bm * 64 + t) * 2 * 8192;
#pragma unroll
    for (int u = 0; u < 8; ++u) {
        const int gid = u * 256 + tid;
        const int h = gid >> 10, rem = gid & 1023;
        const int row = rem >> 2, slot = rem & 3;
        const int kslot = slot ^ ((row >> 1) & 3);
        const float* s = x + (size_t)(bm * 256 + row) * H_DIM
                           + t * 64 + h * 32 + kslot * 8;
        f32x4 a = ((const f32x4*)s)[0], b = ((const f32x4*)s)[1];
        uint4 o;
        o.x = bf16_rn(a[0]) | (bf16_rn(a[1]) << 16);
        o.y = bf16_rn(a[2]) | (bf16_rn(a[3]) << 16);
        o.z = bf16_rn(b[0]) | (bf16_rn(b[1]) << 16);
        o.w = bf16_rn(b[2]) | (bf16_rn(b[3]) << 16);
        *(uint4*)(panA + ubase + (size_t)h * 8192 + row * 32 + slot * 8) = o;
    }
}

// ---------------------------------------------------------------------------
// Prepass 1b: x fp32 -> panA (hi) + panAl (lo).  [tier-1]
// ---------------------------------------------------------------------------
__global__ __launch_bounds__(256) void build_xA_panels_hl(
    const float* __restrict__ x, unsigned short* __restrict__ panA,
    unsigned short* __restrict__ panAl)
{
    const int t = blockIdx.x, bm = blockIdx.y, tid = threadIdx.x;
    const size_t ubase = (size_t)(bm * 64 + t) * 2 * 8192;
#pragma unroll
    for (int u = 0; u < 8; ++u) {
        const int gid = u * 256 + tid;
        const int h = gid >> 10, rem = gid & 1023;
        const int row = rem >> 2, slot = rem & 3;
        const int kslot = slot ^ ((row >> 1) & 3);
        const float* s = x + (size_t)(bm * 256 + row) * H_DIM
                           + t * 64 + h * 32 + kslot * 8;
        f32x4 a = ((const f32x4*)s)[0], b = ((const f32x4*)s)[1];
        unsigned int hb[8], lb[8];
        float v[8] = {a[0], a[1], a[2], a[3], b[0], b[1], b[2], b[3]};
#pragma unroll
        for (int q = 0; q < 8; ++q) {
            hb[q] = bf16_rn(v[q]);
            lb[q] = bf16_rn(v[q] - bf16f(hb[q]));
        }
        uint4 oh, ol;
        oh.x = hb[0] | (hb[1] << 16); oh.y = hb[2] | (hb[3] << 16);
        oh.z = hb[4] | (hb[5] << 16); oh.w = hb[6] | (hb[7] << 16);
        ol.x = lb[0] | (lb[1] << 16); ol.y = lb[2] | (lb[3] << 16);
        ol.z = lb[4] | (lb[5] << 16); ol.w = lb[6] | (lb[7] << 16);
        const size_t idx = ubase + (size_t)h * 8192 + row * 32 + slot * 8;
        *(uint4*)(panA + idx)  = oh;
        *(uint4*)(panAl + idx) = ol;
    }
}

// ---------------------------------------------------------------------------
// Prepass 2: We1[e][k][d] fp32 -> panB[nbG(64)][TT(128)]{16KB unit}.
// ---------------------------------------------------------------------------
__global__ __launch_bounds__(256) void build_w1B_panels(
    const float* __restrict__ We1, unsigned short* __restrict__ panB)
{
    __shared__ unsigned short tile[64][72];
    const int dblk = blockIdx.x, t = blockIdx.y, e = blockIdx.z;
    const int tid = threadIdx.x;
    {
        const int kr = tid >> 2, c0 = (tid & 3) * 16;
        const float* s = We1 + ((size_t)e * H_DIM + t * 64 + kr) * H2_DIM
                             + dblk * 64 + c0;
#pragma unroll
        for (int q = 0; q < 4; ++q) {
            f32x4 v = ((const f32x4*)s)[q];
            tile[kr][c0 + q * 4 + 0] = (unsigned short)bf16_rn(v[0]);
            tile[kr][c0 + q * 4 + 1] = (unsigned short)bf16_rn(v[1]);
            tile[kr][c0 + q * 4 + 2] = (unsigned short)bf16_rn(v[2]);
            tile[kr][c0 + q * 4 + 3] = (unsigned short)bf16_rn(v[3]);
        }
    }
    __syncthreads();
    const int nbG = e * 8 + (dblk >> 2);
    const int col = tid >> 2, slot = tid & 3;
    const int colg = (dblk & 3) * 64 + col;
    const int kslot = slot ^ ((colg >> 1) & 3);
#pragma unroll
    for (int hh = 0; hh < 2; ++hh) {
        const int kl = hh * 32 + kslot * 8;
        uint4 o;
        o.x = (unsigned int)tile[kl + 0][col] | ((unsigned int)tile[kl + 1][col] << 16);
        o.y = (unsigned int)tile[kl + 2][col] | ((unsigned int)tile[kl + 3][col] << 16);
        o.z = (unsigned int)tile[kl + 4][col] | ((unsigned int)tile[kl + 5][col] << 16);
        o.w = (unsigned int)tile[kl + 6][col] | ((unsigned int)tile[kl + 7][col] << 16);
        *(uint4*)(panB + (((size_t)nbG * 64 + t) * 2 + hh) * 8192
                        + colg * 32 + slot * 8) = o;
    }
}

// ---------------------------------------------------------------------------
// Prepass 3: Wg1 -> panBgh/panBgl hi/lo panels (gate).
// ---------------------------------------------------------------------------
__global__ __launch_bounds__(256) void build_wg1_panels(
    const float* __restrict__ Wg1, unsigned short* __restrict__ panBgh,
    unsigned short* __restrict__ panBgl)
{
    __shared__ unsigned short tileH[64][72];
    __shared__ unsigned short tileL[64][72];
    const int dblk = blockIdx.x, t = blockIdx.y;
    const int tid = threadIdx.x;
    {
        const int kr = tid >> 2, c0 = (tid & 3) * 16;
        const float* s = Wg1 + ((size_t)t * 64 + kr) * H2_DIM + dblk * 64 + c0;
#pragma unroll
        for (int q = 0; q < 4; ++q) {
            f32x4 v = ((const f32x4*)s)[q];
#pragma unroll
            for (int j = 0; j < 4; ++j) {
                const unsigned int hb = bf16_rn(v[j]);
                tileH[kr][c0 + q * 4 + j] = (unsigned short)hb;
                tileL[kr][c0 + q * 4 + j] =
                    (unsigned short)bf16_rn(v[j] - bf16f(hb));
            }
        }
    }
    __syncthreads();
    const int nbG = dblk >> 1;
    const int col = tid >> 2, slot = tid & 3;
    const int colg = (dblk & 1) * 64 + col;
    const int kslot = slot ^ ((colg >> 1) & 3);
#pragma unroll
    for (int hh = 0; hh < 2; ++hh) {
        const int kl = hh * 32 + kslot * 8;
        uint4 oh, ol;
        oh.x = (unsigned int)tileH[kl + 0][col] | ((unsigned int)tileH[kl + 1][col] << 16);
        oh.y = (unsigned int)tileH[kl + 2][col] | ((unsigned int)tileH[kl + 3][col] << 16);
        oh.z = (unsigned int)tileH[kl + 4][col] | ((unsigned int)tileH[kl + 5][col] << 16);
        oh.w = (unsigned int)tileH[kl + 6][col] | ((unsigned int)tileH[kl + 7][col] << 16);
        ol.x = (unsigned int)tileL[kl + 0][col] | ((unsigned int)tileL[kl + 1][col] << 16);
        ol.y = (unsigned int)tileL[kl + 2][col] | ((unsigned int)tileL[kl + 3][col] << 16);
        ol.z = (unsigned int)tileL[kl + 4][col] | ((unsigned int)tileL[kl + 5][col] << 16);
        ol.w = (unsigned int)tileL[kl + 6][col] | ((unsigned int)tileL[kl + 7][col] << 16);
        const size_t idx = (((size_t)nbG * 64 + t) * 2 + hh) * 4096
                         + colg * 32 + slot * 8;
        *(uint4*)(panBgh + idx) = oh;
        *(uint4*)(panBgl + idx) = ol;
    }
}

// ---------------------------------------------------------------------------
// Gate GEMM R20: A double-buffered via LDS (stage-ahead-1), B direct to
// registers from pre-swizzled panBg units (coalesced; issued before the A
// stage so the compiler's B-wait is a counted vmcnt). Math = R16 exactly.
// LDS 44KB -> 3 blocks/CU.
// ---------------------------------------------------------------------------
__global__ __launch_bounds__(256, 3) void moe_gate_panel(
    const unsigned short* __restrict__ panA, const unsigned short* __restrict__ panAl,
    const unsigned short* __restrict__ panBgh, const unsigned short* __restrict__ panBgl,
    const float* __restrict__ bg1, const float* __restrict__ Wg2,
    float* __restrict__ gpart)
{
    __shared__ short lAh[2][4096], lAl[2][4096];   // 32KB
    __shared__ float lW2[128 * 8];                 // 4KB
    __shared__ float gred[2][128][8];              // 8KB

    const int tid  = threadIdx.x;
    const int lane = tid & 63;
    const int wv   = tid >> 6;
    const int wm   = wv >> 1;
    const int wn   = wv & 1;
    const int nb = blockIdx.x;
    const int bm = blockIdx.y;
    const int dbase = nb * 128;

    const char* AhB = (const char*)panA  + ((size_t)(bm >> 1) << 21)
                                         + ((size_t)(bm & 1) << 13);
    const char* AlB = (const char*)panAl + ((size_t)(bm >> 1) << 21)
                                         + ((size_t)(bm & 1) << 13);
    const char* BhB = (const char*)panBgh + ((size_t)nb << 20);
    const char* BlB = (const char*)panBgl + ((size_t)nb << 20);

    {
        const f32x4* s = reinterpret_cast<const f32x4*>(Wg2 + (size_t)dbase * 8);
        reinterpret_cast<f32x4*>(lW2)[tid] = s[tid];
    }

    const int rA = wm * 64 + (lane & 15);
    const int offA = rA * 64 + ((((lane >> 4)) ^ ((rA >> 1) & 3)) << 4);
    const int rB = wn * 64 + (lane & 15);
    const int offB = rB * 64 + ((((lane >> 4)) ^ ((rB >> 1) & 3)) << 4);

    f32x4 acc[4][4];
#pragma unroll
    for (int i = 0; i < 4; ++i)
#pragma unroll
        for (int j = 0; j < 4; ++j) acc[i][j] = (f32x4){0.f, 0.f, 0.f, 0.f};

#define GRD8(BASE, OFF) \
    (*reinterpret_cast<const short8*>(reinterpret_cast<const char*>(BASE) + (OFF)))

#define ASTAGE(TT, CC) do {                                                    \
    const char* ua = AhB + ((size_t)(TT) << 14);                               \
    gload_lds16(ua + tid * 16,        (char*)&lAh[CC][0] + wv * 1024);         \
    gload_lds16(ua + 4096 + tid * 16, (char*)&lAh[CC][0] + 4096 + wv * 1024);  \
    const char* ul = AlB + ((size_t)(TT) << 14);                               \
    gload_lds16(ul + tid * 16,        (char*)&lAl[CC][0] + wv * 1024);         \
    gload_lds16(ul + 4096 + tid * 16, (char*)&lAl[CC][0] + 4096 + wv * 1024);  \
} while (0)

// One K-tile (buf CC holds A(T)): load B(T) to regs FIRST (oldest in vmem
// queue), then stage A(TN)->CC^1 (youngest). Compiler's wait for the B regs
// is a counted vmcnt that leaves the A stage in flight under the MFMAs.
// End: vmcnt(0) (drains only the 4 A loads, issued a whole tile ago) +
// barrier. RAW on A(T): drained by previous iteration's vmcnt(0)+barrier.
// WAR on CC^1: last read one collective barrier earlier.
#define GITER(CC, TT, TN) do {                                                 \
    short8 bh[4], bl[4];                                                       \
    {                                                                          \
        const char* ub = BhB + ((size_t)(TT) << 13);                           \
        const char* vb = BlB + ((size_t)(TT) << 13);                           \
        _Pragma("unroll")                                                      \
        for (int n = 0; n < 4; ++n) {                                          \
            bh[n] = GRD8(ub, offB + n * 1024);                                 \
            bl[n] = GRD8(vb, offB + n * 1024);                                 \
        }                                                                      \
    }                                                                          \
    ASTAGE(TN, (CC) ^ 1);                                                      \
    short8 ah[4], al[4];                                                       \
    _Pragma("unroll")                                                          \
    for (int i = 0; i < 4; ++i) {                                              \
        ah[i] = GRD8(&lAh[CC][0], offA + i * 1024);                            \
        al[i] = GRD8(&lAl[CC][0], offA + i * 1024);                            \
    }                                                                          \
    __builtin_amdgcn_s_setprio(1);                                             \
    _Pragma("unroll")                                                          \
    for (int i = 0; i < 4; ++i)                                                \
        _Pragma("unroll")                                                      \
        for (int n = 0; n < 4; ++n) {                                          \
            acc[i][n] = __builtin_amdgcn_mfma_f32_16x16x32_bf16(ah[i], bh[n], acc[i][n], 0, 0, 0); \
            acc[i][n] = __builtin_amdgcn_mfma_f32_16x16x32_bf16(ah[i], bl[n], acc[i][n], 0, 0, 0); \
            acc[i][n] = __builtin_amdgcn_mfma_f32_16x16x32_bf16(al[i], bh[n], acc[i][n], 0, 0, 0); \
        }                                                                      \
    __builtin_amdgcn_s_setprio(0);                                             \
    asm volatile("s_waitcnt vmcnt(0)");                                        \
    __builtin_amdgcn_s_barrier();                                              \
} while (0)

    ASTAGE(0, 0);
    asm volatile("s_waitcnt vmcnt(0)");
    __builtin_amdgcn_s_barrier();

    for (int t = 0; t < 128; t += 2) {
        GITER(0, t, t + 1);                           // t+1 <= 127 always
        GITER(1, t + 1, (t + 2 < 128) ? t + 2 : 127); // last: dummy restage
    }
    asm volatile("s_waitcnt vmcnt(0)");
#undef GITER
#undef ASTAGE

    const int c = lane & 15, g = lane >> 4;
    float bgv[4];
#pragma unroll
    for (int ni = 0; ni < 4; ++ni) bgv[ni] = bg1[dbase + wn * 64 + ni * 16 + c];
#pragma unroll
    for (int mi = 0; mi < 4; ++mi) {
#pragma unroll
        for (int r = 0; r < 4; ++r) {
            float gv[4];
#pragma unroll
            for (int ni = 0; ni < 4; ++ni)
                gv[ni] = fmaxf(acc[mi][ni][r] + bgv[ni], 0.f);
#pragma unroll
            for (int e8 = 0; e8 < 8; ++e8) {
                float tsum = 0.f;
#pragma unroll
                for (int ni = 0; ni < 4; ++ni)
                    tsum = fmaf(gv[ni], lW2[(wn * 64 + ni * 16 + c) * 8 + e8], tsum);
                tsum += __shfl_xor(tsum, 1);
                tsum += __shfl_xor(tsum, 2);
                tsum += __shfl_xor(tsum, 4);
                tsum += __shfl_xor(tsum, 8);
                if (c == e8) gred[wn][wm * 64 + mi * 16 + g * 4 + r][e8] = tsum;
            }
        }
    }
    __syncthreads();
    {
        const int row = tid & 127;
        const int ebase = (tid >> 7) * 4;
        const int b = bm * 128 + row;
#pragma unroll
        for (int i = 0; i < 4; ++i) {
            const int e8 = ebase + i;
            gpart[(size_t)b * 128 + nb * 8 + e8] =
                gred[0][row][e8] + gred[1][row][e8];
        }
    }
}
#undef GRD8

// ---------------------------------------------------------------------------
// Routing: zero counters; logits+top2+list build; tile table.
// ---------------------------------------------------------------------------
__global__ void route_zero(int* __restrict__ cnt) {
    if (threadIdx.x < E_DIM) cnt[threadIdx.x] = 0;
}

__global__ __launch_bounds__(256) void moe_logits_topk(
    const float* __restrict__ gpart, const float* __restrict__ bg2,
    int* __restrict__ sel, float* __restrict__ w2f,
    int* __restrict__ cnt, int* __restrict__ tokenlist)
{
    const int b = blockIdx.x * 256 + threadIdx.x;
    float logit[8];
#pragma unroll
    for (int e = 0; e < 8; ++e) logit[e] = bg2[e];
    const float* gp = gpart + (size_t)b * 128;
#pragma unroll
    for (int cN = 0; cN < 16; ++cN)
#pragma unroll
        for (int e = 0; e < 8; ++e) logit[e] += gp[cN * 8 + e];

    int i1 = 0; float m1 = logit[0];
#pragma unroll
    for (int e = 1; e < 8; ++e) if (logit[e] > m1) { m1 = logit[e]; i1 = e; }
    int i2 = -1; float m2 = -3.4e38f;
#pragma unroll
    for (int e = 0; e < 8; ++e) if (e != i1 && logit[e] > m2) { m2 = logit[e]; i2 = e; }

    sel[b] = i1 | (i2 << 8);
    w2f[b] = expf(m2 - m1);
    const int p1 = atomicAdd(&cnt[i1], 1);
    tokenlist[i1 * B_DIM + p1] = (b << 1);
    const int p2 = atomicAdd(&cnt[i2], 1);
    tokenlist[i2 * B_DIM + p2] = (b << 1) | 1;
}

__global__ void moe_tiletab(
    const int* __restrict__ cnt, int* __restrict__ tileE,
    int* __restrict__ tileB, int* __restrict__ nTiles)
{
    if (threadIdx.x == 0) {
        int tot = 0;
        for (int e = 0; e < E_DIM; ++e) {
            const int nt = (cnt[e] + 127) >> 7;
            for (int j = 0; j < nt; ++j) { tileE[tot] = e; tileB[tot] = j; ++tot; }
        }
        *nTiles = tot;
    }
}

// ---------------------------------------------------------------------------
// Sparse expert GEMM (R16 verified): R10 3-buffer pipeline, gathered A,
// chunk-fastest grid. Output esel[token][slot(2)][chunk(8)].
// ---------------------------------------------------------------------------
__global__ __launch_bounds__(512, 4) void moe_expert_sparse(
    const unsigned short* __restrict__ panA, const unsigned short* __restrict__ panB,
    const float* __restrict__ be1, const float* __restrict__ We2,
    const int* __restrict__ tileE, const int* __restrict__ tileB,
    const int* __restrict__ nTiles, const int* __restrict__ cnt,
    const int* __restrict__ tokenlist, float* __restrict__ esel)
{
    __shared__ short lA[3][4096];
    __shared__ short lB[3][8192];
    __shared__ float red[4][128];
    __shared__ int   tokbuf[128];

    const int tix = blockIdx.y;
    if (tix >= *nTiles) return;
    const int chunk = blockIdx.x;

    const int tid  = threadIdx.x;
    const int lane = tid & 63;
    const int wv   = tid >> 6;
    const int wm   = wv >> 2;
    const int wn   = wv & 3;

    const int e  = tileE[tix];
    const int tb = tileB[tix];
    const int ce = cnt[e];
    const int nb = e * 8 + chunk;
    const int dbase = chunk * 256;

    if (tid < 128) {
        const int gi = tb * 128 + tid;
        tokbuf[tid] = (gi < ce) ? tokenlist[e * B_DIM + gi] : -1;
    }
    __syncthreads();

    const int rawT = tokbuf[tid >> 2];
    const int tokv = ((rawT < 0) ? tokbuf[0] : rawT) >> 1;
    const int trow = tokv & 255;
    const int lr = tid >> 2, ls = tid & 3;
    const int sslot = ls ^ ((lr >> 1) & 3) ^ ((trow >> 1) & 3);
    const char* Asrc = (const char*)panA + ((size_t)(tokv >> 8) << 21)
                     + trow * 64 + sslot * 16;
    const char* Bbase = (const char*)panB + ((size_t)nb << 21);

#define STAGE(TT, CC) do {                                                     \
    gload_lds16(Asrc + ((size_t)(TT) << 14), (char*)&lA[CC][0] + wv * 1024);   \
    const char* ub_ = Bbase + ((size_t)(TT) << 14);                            \
    gload_lds16(ub_ + tid * 16, (char*)&lB[CC][0] + wv * 1024);                \
    gload_lds16(ub_ + 8192 + tid * 16, (char*)&lB[CC][0] + 8192 + wv * 1024);  \
} while (0)

#define RD8(BASE, OFF) \
    (*reinterpret_cast<const short8*>(reinterpret_cast<const char*>(BASE) + (OFF)))

    const int rA = wm * 64 + (lane & 15);
    const int offA = rA * 64 + ((((lane >> 4)) ^ ((rA >> 1) & 3)) << 4);
    const int rB = wn * 64 + (lane & 15);
    const int offB = rB * 64 + ((((lane >> 4)) ^ ((rB >> 1) & 3)) << 4);

    f32x4 acc[4][4];
#pragma unroll
    for (int i = 0; i < 4; ++i)
#pragma unroll
        for (int j = 0; j < 4; ++j) acc[i][j] = (f32x4){0.f, 0.f, 0.f, 0.f};

    STAGE(0, 0);
    STAGE(1, 1);
    asm volatile("s_waitcnt vmcnt(3)");
    __builtin_amdgcn_s_barrier();

#define ITER(CUR, NXT, TN) do {                                                \
    STAGE(TN, NXT);                                                            \
    short8 af_[4], bf_[4];                                                     \
    _Pragma("unroll")                                                          \
    for (int i = 0; i < 4; ++i) af_[i] = RD8(&lA[CUR][0], offA + i * 1024);    \
    _Pragma("unroll")                                                          \
    for (int n = 0; n < 4; ++n) bf_[n] = RD8(&lB[CUR][0], offB + n * 1024);    \
    __builtin_amdgcn_s_setprio(1);                                             \
    _Pragma("unroll")                                                          \
    for (int i = 0; i < 4; ++i)                                                \
        _Pragma("unroll")                                                      \
        for (int n = 0; n < 4; ++n)                                            \
            acc[i][n] = __builtin_amdgcn_mfma_f32_16x16x32_bf16(af_[i], bf_[n], acc[i][n], 0, 0, 0); \
    __builtin_amdgcn_s_setprio(0);                                             \
    asm volatile("s_waitcnt vmcnt(3)");                                        \
    __builtin_amdgcn_s_barrier();                                              \
} while (0)

    for (int t = 0; t < 126; t += 3) {
        ITER(0, 2, t + 2);
        ITER(1, 0, t + 3);
        ITER(2, 1, t + 4);
    }
    ITER(0, 2, 127);
    ITER(1, 0, 127);
    asm volatile("s_waitcnt vmcnt(0)");
#undef ITER
#undef STAGE

    const int cc = lane & 15, g = lane >> 4;
    float w2v[4], b1v[4];
#pragma unroll
    for (int ni = 0; ni < 4; ++ni) {
        const int d = dbase + wn * 64 + ni * 16 + cc;
        b1v[ni] = be1[e * H2_DIM + d];
        w2v[ni] = We2[e * H2_DIM + d];
    }
#pragma unroll
    for (int mi = 0; mi < 4; ++mi) {
#pragma unroll
        for (int r = 0; r < 4; ++r) {
            float s = 0.f;
#pragma unroll
            for (int ni = 0; ni < 4; ++ni) {
                float v = acc[mi][ni][r] + b1v[ni];
                v = fmaxf(v, 0.f);
                s = fmaf(v, w2v[ni], s);
            }
            s += __shfl_xor(s, 1);
            s += __shfl_xor(s, 2);
            s += __shfl_xor(s, 4);
            s += __shfl_xor(s, 8);
            if (cc == 0) red[wn][wm * 64 + mi * 16 + g * 4 + r] = s;
        }
    }
    __syncthreads();
    if (tid < 128) {
        const int r2 = tokbuf[tid];
        if (r2 >= 0) {
            const int tk = r2 >> 1, sl = r2 & 1;
            esel[(size_t)tk * 16 + sl * 8 + chunk] =
                red[0][tid] + red[1][tid] + red[2][tid] + red[3][tid];
        }
    }
}

// ---------------------------------------------------------------------------
// Sparse finalize: combine the two selected experts.
// ---------------------------------------------------------------------------
__global__ __launch_bounds__(256) void moe_finalize_sparse(
    const float* __restrict__ esel, const int* __restrict__ sel,
    const float* __restrict__ w2f, const float* __restrict__ be2,
    float* __restrict__ out)
{
    const int b = blockIdx.x * 256 + threadIdx.x;
    const int s = sel[b];
    const int i1 = s & 255, i2 = (s >> 8) & 255;
    const float w2 = w2f[b];
    const float* ep = esel + (size_t)b * 16;
    float eo1 = be2[i1], eo2 = be2[i2];
#pragma unroll
    for (int c = 0; c < 8; ++c) eo1 += ep[c];
#pragma unroll
    for (int c = 0; c < 8; ++c) eo2 += ep[8 + c];
    out[b] = (eo1 + w2 * eo2) / (1.f + w2);
}

// ---------------------------------------------------------------------------
// Dense expert GEMM (R10 verbatim) — tier-2.
// ---------------------------------------------------------------------------
__global__ __launch_bounds__(512, 4) void moe_expert_gemm_128(
    const unsigned short* __restrict__ panA, const unsigned short* __restrict__ panB,
    const float* __restrict__ be1, const float* __restrict__ We2,
    float* __restrict__ epart)
{
    __shared__ short lA[3][4096];
    __shared__ short lB[3][8192];
    __shared__ float red[4][128];

    const int tid  = threadIdx.x;
    const int lane = tid & 63;
    const int wv   = tid >> 6;
    const int wm   = wv >> 2;
    const int wn   = wv & 3;

    const int lin = blockIdx.x;
    const int sb  = lin >> 8, i5 = lin & 255;
    const int sbm = sb & 7, snb = sb >> 3;
    const int xcd = i5 & 7, j5 = i5 >> 3;
    const int bm  = sbm * 16 + (xcd & 1) * 8 + (j5 & 7);
    const int nb  = snb * 16 + (xcd >> 1) * 4 + (j5 >> 3);
    const int e = nb >> 3, chunk = nb & 7;
    const int dbase = chunk * 256;

    const char* Abase = (const char*)panA + ((size_t)(bm >> 1) << 21)
                                          + ((size_t)(bm & 1) << 13);
    const char* Bbase = (const char*)panB + ((size_t)nb << 21);

#define STAGE(TT, CC) do {                                                     \
    const char* ua_ = Abase + ((size_t)(TT) << 14);                            \
    gload_lds16(ua_ + tid * 16, (char*)&lA[CC][0] + wv * 1024);                \
    const char* ub_ = Bbase + ((size_t)(TT) << 14);                            \
    gload_lds16(ub_ + tid * 16, (char*)&lB[CC][0] + wv * 1024);                \
    gload_lds16(ub_ + 8192 + tid * 16, (char*)&lB[CC][0] + 8192 + wv * 1024);  \
} while (0)

#define RD8(BASE, OFF) \
    (*reinterpret_cast<const short8*>(reinterpret_cast<const char*>(BASE) + (OFF)))

    const int rA = wm * 64 + (lane & 15);
    const int offA = rA * 64 + ((((lane >> 4)) ^ ((rA >> 1) & 3)) << 4);
    const int rB = wn * 64 + (lane & 15);
    const int offB = rB * 64 + ((((lane >> 4)) ^ ((rB >> 1) & 3)) << 4);

    f32x4 acc[4][4];
#pragma unroll
    for (int i = 0; i < 4; ++i)
#pragma unroll
        for (int j = 0; j < 4; ++j) acc[i][j] = (f32x4){0.f, 0.f, 0.f, 0.f};

    STAGE(0, 0);
    STAGE(1, 1);
    asm volatile("s_waitcnt vmcnt(3)");
    __builtin_amdgcn_s_barrier();

#define ITER(CUR, NXT, TN) do {                                                \
    STAGE(TN, NXT);                                                            \
    short8 af_[4], bf_[4];                                                     \
    _Pragma("unroll")                                                          \
    for (int i = 0; i < 4; ++i) af_[i] = RD8(&lA[CUR][0], offA + i * 1024);    \
    _Pragma("unroll")                                                          \
    for (int n = 0; n < 4; ++n) bf_[n] = RD8(&lB[CUR][0], offB + n * 1024);    \
    __builtin_amdgcn_s_setprio(1);                                             \
    _Pragma("unroll")                                                          \
    for (int i = 0; i < 4; ++i)                                                \
        _Pragma("unroll")                                                      \
        for (int n = 0; n < 4; ++n)                                            \
            acc[i][n] = __builtin_amdgcn_mfma_f32_16x16x32_bf16(af_[i], bf_[n], acc[i][n], 0, 0, 0); \
    __builtin_amdgcn_s_setprio(0);                                             \
    asm volatile("s_waitcnt vmcnt(3)");                                        \
    __builtin_amdgcn_s_barrier();                                              \
} while (0)

    for (int t = 0; t < 126; t += 3) {
        ITER(0, 2, t + 2);
        ITER(1, 0, t + 3);
        ITER(2, 1, t + 4);
    }
    ITER(0, 2, 127);
    ITER(1, 0, 127);
    asm volatile("s_waitcnt vmcnt(0)");
#undef ITER
#undef STAGE

    const int cc = lane & 15, g = lane >> 4;
    float w2v[4], b1v[4];
#pragma unroll
    for (int ni = 0; ni < 4; ++ni) {
        const int d = dbase + wn * 64 + ni * 16 + cc;
        b1v[ni] = be1[e * H2_DIM + d];
        w2v[ni] = We2[e * H2_DIM + d];
    }
#pragma unroll
    for (int mi = 0; mi < 4; ++mi) {
#pragma unroll
        for (int r = 0; r < 4; ++r) {
            float s = 0.f;
#pragma unroll
            for (int ni = 0; ni < 4; ++ni) {
                float v = acc[mi][ni][r] + b1v[ni];
                v = fmaxf(v, 0.f);
                s = fmaf(v, w2v[ni], s);
            }
            s += __shfl_xor(s, 1);
            s += __shfl_xor(s, 2);
            s += __shfl_xor(s, 4);
            s += __shfl_xor(s, 8);
            if (cc == 0) red[wn][wm * 64 + mi * 16 + g * 4 + r] = s;
        }
    }
    __syncthreads();
    if (tid < 128) {
        const int b = bm * 128 + tid;
        epart[((size_t)b * E_DIM + e) * 8 + chunk] =
            red[0][tid] + red[1][tid] + red[2][tid] + red[3][tid];
    }
}

// ---------------------------------------------------------------------------
// Fallback gate GEMM (fp32 in-kernel split) — round-1 verified. [tier-2/3]
// ---------------------------------------------------------------------------
__global__ __launch_bounds__(256, 2) void moe_gate_gemm(
    const float* __restrict__ x, const float* __restrict__ Wg1,
    const float* __restrict__ bg1, const float* __restrict__ Wg2,
    float* __restrict__ gpart)
{
    __shared__ short lAh[128 * 64], lAl[128 * 64];
    __shared__ short lBh[128 * 64], lBl[128 * 64];
    __shared__ float lW2[128 * 8];
    __shared__ float gred[2][128][8];

    const int tid  = threadIdx.x;
    const int lane = tid & 63;
    const int wm = (tid >> 6) >> 1, wn = (tid >> 6) & 1;
    const int nb = blockIdx.x, bm = blockIdx.y;
    const int dbase = nb * 128;

    const float* Asrc = x + (size_t)bm * 128 * H_DIM;
    const float* Bsrc = Wg1 + dbase;

    {
        const f32x4* s = reinterpret_cast<const f32x4*>(Wg2 + (size_t)dbase * 8);
        reinterpret_cast<f32x4*>(lW2)[tid] = s[tid];
    }

    f32x4 acc[4][4];
#pragma unroll
    for (int i = 0; i < 4; ++i)
#pragma unroll
        for (int j = 0; j < 4; ++j) acc[i][j] = (f32x4){0.f, 0.f, 0.f, 0.f};

    const int arow0 = tid >> 4, af4 = tid & 15;
    const int bn = tid & 127, bkc0 = tid >> 7;

    for (int k0 = 0; k0 < H_DIM; k0 += 64) {
        __syncthreads();
#pragma unroll
        for (int j = 0; j < 8; ++j) {
            const int row = arow0 + j * 16;
            const float* p = Asrc + (size_t)row * H_DIM + k0 + af4 * 4;
            float a[4] = {p[0], p[1], p[2], p[3]};
            unsigned int hb[4], lb[4];
#pragma unroll
            for (int q = 0; q < 4; ++q) {
                hb[q] = bf16_rn(a[q]);
                lb[q] = bf16_rn(a[q] - bf16f(hb[q]));
            }
            const int byte = row * 128 + ((af4 * 8) ^ ((row & 7) << 4));
            *reinterpret_cast<uint2*>(reinterpret_cast<char*>(lAh) + byte) =
                make_uint2(hb[0] | (hb[1] << 16), hb[2] | (hb[3] << 16));
            *reinterpret_cast<uint2*>(reinterpret_cast<char*>(lAl) + byte) =
                make_uint2(lb[0] | (lb[1] << 16), lb[2] | (lb[3] << 16));
        }
#pragma unroll
        for (int j = 0; j < 4; ++j) {
            const int kc = bkc0 + 2 * j;
            const float* p = Bsrc + (size_t)(k0 + kc * 8) * H2_DIM + bn;
            unsigned int hb[8], lb[8];
#pragma unroll
            for (int q = 0; q < 8; ++q) {
                float v = p[(size_t)q * H2_DIM];
                hb[q] = bf16_rn(v);
                lb[q] = bf16_rn(v - bf16f(hb[q]));
            }
            const int byte = bn * 128 + ((kc * 16) ^ ((bn & 7) << 4));
            *reinterpret_cast<uint4*>(reinterpret_cast<char*>(lBh) + byte) =
                make_uint4(hb[0] | (hb[1] << 16), hb[2] | (hb[3] << 16),
                           hb[4] | (hb[5] << 16), hb[6] | (hb[7] << 16));
            *reinterpret_cast<uint4*>(reinterpret_cast<char*>(lBl) + byte) =
                make_uint4(lb[0] | (lb[1] << 16), lb[2] | (lb[3] << 16),
                           lb[4] | (lb[5] << 16), lb[6] | (lb[7] << 16));
        }
        __syncthreads();
#pragma unroll
        for (int kk = 0; kk < 2; ++kk) {
            const int kbyte = kk * 64 + ((lane >> 4) << 4);
            short8 ah[4], al[4], bh[4], bl[4];
#pragma unroll
            for (int mi = 0; mi < 4; ++mi) {
                const int r = wm * 64 + mi * 16 + (lane & 15);
                const int off = r * 128 + (kbyte ^ ((r & 7) << 4));
                ah[mi] = *reinterpret_cast<const short8*>(reinterpret_cast<const char*>(lAh) + off);
                al[mi] = *reinterpret_cast<const short8*>(reinterpret_cast<const char*>(lAl) + off);
            }
#pragma unroll
            for (int ni = 0; ni < 4; ++ni) {
                const int r = wn * 64 + ni * 16 + (lane & 15);
                const int off = r * 128 + (kbyte ^ ((r & 7) << 4));
                bh[ni] = *reinterpret_cast<const short8*>(reinterpret_cast<const char*>(lBh) + off);
                bl[ni] = *reinterpret_cast<const short8*>(reinterpret_cast<const char*>(lBl) + off);
            }
#pragma unroll
            for (int mi = 0; mi < 4; ++mi)
#pragma unroll
                for (int ni = 0; ni < 4; ++ni) {
                    acc[mi][ni] = __builtin_amdgcn_mfma_f32_16x16x32_bf16(ah[mi], bh[ni], acc[mi][ni], 0, 0, 0);
                    acc[mi][ni] = __builtin_amdgcn_mfma_f32_16x16x32_bf16(ah[mi], bl[ni], acc[mi][ni], 0, 0, 0);
                    acc[mi][ni] = __builtin_amdgcn_mfma_f32_16x16x32_bf16(al[mi], bh[ni], acc[mi][ni], 0, 0, 0);
                }
        }
    }

    const int c = lane & 15, g = lane >> 4;
    float bgv[4];
#pragma unroll
    for (int ni = 0; ni < 4; ++ni) bgv[ni] = bg1[dbase + wn * 64 + ni * 16 + c];
#pragma unroll
    for (int mi = 0; mi < 4; ++mi) {
#pragma unroll
        for (int r = 0; r < 4; ++r) {
            float gv[4];
#pragma unroll
            for (int ni = 0; ni < 4; ++ni)
                gv[ni] = fmaxf(acc[mi][ni][r] + bgv[ni], 0.f);
#pragma unroll
            for (int e8 = 0; e8 < 8; ++e8) {
                float t = 0.f;
#pragma unroll
                for (int ni = 0; ni < 4; ++ni)
                    t = fmaf(gv[ni], lW2[(wn * 64 + ni * 16 + c) * 8 + e8], t);
                t += __shfl_xor(t, 1);
                t += __shfl_xor(t, 2);
                t += __shfl_xor(t, 4);
                t += __shfl_xor(t, 8);
                if (c == e8) gred[wn][wm * 64 + mi * 16 + g * 4 + r][e8] = t;
            }
        }
    }
    __syncthreads();
    {
        const int row = tid & 127;
        const int ebase = (tid >> 7) * 4;
        const int b = bm * 128 + row;
#pragma unroll
        for (int i = 0; i < 4; ++i) {
            const int e8 = ebase + i;
            gpart[(size_t)b * 128 + nb * 8 + e8] = gred[0][row][e8] + gred[1][row][e8];
        }
    }
}

// ---------------------------------------------------------------------------
// Fallback expert GEMM (fp32 in-kernel conversion) — round-1 verified. [tier-3]
// ---------------------------------------------------------------------------
__global__ __launch_bounds__(256, 2) void moe_expert_gemm(
    const float* __restrict__ x, const float* __restrict__ We1,
    const float* __restrict__ be1, const float* __restrict__ We2,
    float* __restrict__ epart)
{
    __shared__ short lA[128 * 64];
    __shared__ short lB[128 * 64];
    __shared__ float red[2][128];

    const int tid  = threadIdx.x;
    const int lane = tid & 63;
    const int wm   = (tid >> 6) >> 1;
    const int wn   = (tid >> 6) & 1;
    const int nb = blockIdx.x, bm = blockIdx.y;
    const int e = nb >> 4, chunk = nb & 15;
    const int dbase = chunk * 128;

    const float* Asrc = x + (size_t)bm * 128 * H_DIM;
    const float* Bsrc = We1 + (size_t)e * H_DIM * H2_DIM + dbase;

    f32x4 acc[4][4];
#pragma unroll
    for (int i = 0; i < 4; ++i)
#pragma unroll
        for (int j = 0; j < 4; ++j) acc[i][j] = (f32x4){0.f, 0.f, 0.f, 0.f};

    const int arow0 = tid >> 4, af4 = tid & 15;
    const int bn = tid & 127, bkc0 = tid >> 7;

    for (int k0 = 0; k0 < H_DIM; k0 += 64) {
        __syncthreads();
#pragma unroll
        for (int j = 0; j < 8; ++j) {
            const int row = arow0 + j * 16;
            const float* p = Asrc + (size_t)row * H_DIM + k0 + af4 * 4;
            float a0 = p[0], a1 = p[1], a2 = p[2], a3 = p[3];
            uint2 wv2;
            wv2.x = bf16_rn(a0) | (bf16_rn(a1) << 16);
            wv2.y = bf16_rn(a2) | (bf16_rn(a3) << 16);
            const int byte = row * 128 + ((af4 * 8) ^ ((row & 7) << 4));
            *reinterpret_cast<uint2*>(reinterpret_cast<char*>(lA) + byte) = wv2;
        }
#pragma unroll
        for (int j = 0; j < 4; ++j) {
            const int kc = bkc0 + 2 * j;
            const float* p = Bsrc + (size_t)(k0 + kc * 8) * H2_DIM + bn;
            uint4 wv4;
            wv4.x = bf16_rn(p[0])          | (bf16_rn(p[H2_DIM])     << 16);
            wv4.y = bf16_rn(p[2 * H2_DIM]) | (bf16_rn(p[3 * H2_DIM]) << 16);
            wv4.z = bf16_rn(p[4 * H2_DIM]) | (bf16_rn(p[5 * H2_DIM]) << 16);
            wv4.w = bf16_rn(p[6 * H2_DIM]) | (bf16_rn(p[7 * H2_DIM]) << 16);
            const int byte = bn * 128 + ((kc * 16) ^ ((bn & 7) << 4));
            *reinterpret_cast<uint4*>(reinterpret_cast<char*>(lB) + byte) = wv4;
        }
        __syncthreads();
#pragma unroll
        for (int kk = 0; kk < 2; ++kk) {
            const int kbyte = kk * 64 + ((lane >> 4) << 4);
            short8 af[4], bfr[4];
#pragma unroll
            for (int mi = 0; mi < 4; ++mi) {
                const int r = wm * 64 + mi * 16 + (lane & 15);
                af[mi] = *reinterpret_cast<const short8*>(
                    reinterpret_cast<const char*>(lA) + r * 128 + (kbyte ^ ((r & 7) << 4)));
            }
#pragma unroll
            for (int ni = 0; ni < 4; ++ni) {
                const int r = wn * 64 + ni * 16 + (lane & 15);
                bfr[ni] = *reinterpret_cast<const short8*>(
                    reinterpret_cast<const char*>(lB) + r * 128 + (kbyte ^ ((r & 7) << 4)));
            }
#pragma unroll
            for (int mi = 0; mi < 4; ++mi)
#pragma unroll
                for (int ni = 0; ni < 4; ++ni)
                    acc[mi][ni] = __builtin_amdgcn_mfma_f32_16x16x32_bf16(
                        af[mi], bfr[ni], acc[mi][ni], 0, 0, 0);
        }
    }

    const int c = lane & 15, g = lane >> 4;
    float w2v[4], b1v[4];
#pragma unroll
    for (int ni = 0; ni < 4; ++ni) {
        const int d = dbase + wn * 64 + ni * 16 + c;
        b1v[ni] = be1[e * H2_DIM + d];
        w2v[ni] = We2[e * H2_DIM + d];
    }
#pragma unroll
    for (int mi = 0; mi < 4; ++mi) {
#pragma unroll
        for (int r = 0; r < 4; ++r) {
            float s = 0.f;
#pragma unroll
            for (int ni = 0; ni < 4; ++ni) {
                float v = acc[mi][ni][r] + b1v[ni];
                v = fmaxf(v, 0.f);
                s = fmaf(v, w2v[ni], s);
            }
            s += __shfl_xor(s, 1);
            s += __shfl_xor(s, 2);
            s += __shfl_xor(s, 4);
            s += __shfl_xor(s, 8);
            if (c == 0) red[wn][wm * 64 + mi * 16 + g * 4 + r] = s;
        }
    }
    __syncthreads();
    if (tid < 128) {
        const int b = bm * 128 + tid;
        epart[((size_t)b * E_DIM + e) * 16 + chunk] = red[0][tid] + red[1][tid];
    }
}

// ---------------------------------------------------------------------------
// Dense finalize — tiers 2/3.
// ---------------------------------------------------------------------------
template <int NC>
__global__ __launch_bounds__(256) void moe_finalize(
    const float* __restrict__ gpart, const float* __restrict__ epart,
    const float* __restrict__ bg2, const float* __restrict__ be2,
    float* __restrict__ out)
{
    const int b = blockIdx.x * 256 + threadIdx.x;
    float logit[8];
#pragma unroll
    for (int e = 0; e < 8; ++e) logit[e] = bg2[e];
    const float* gp = gpart + (size_t)b * 128;
#pragma unroll
    for (int cN = 0; cN < 16; ++cN)
#pragma unroll
        for (int e = 0; e < 8; ++e) logit[e] += gp[cN * 8 + e];

    float eo[8];
    const float* ep = epart + (size_t)b * E_DIM * NC;
#pragma unroll
    for (int e = 0; e < 8; ++e) {
        float s = be2[e];
#pragma unroll
        for (int cN = 0; cN < NC; ++cN) s += ep[e * NC + cN];
        eo[e] = s;
    }

    int i1 = 0; float m1 = logit[0];
#pragma unroll
    for (int e = 1; e < 8; ++e) if (logit[e] > m1) { m1 = logit[e]; i1 = e; }
    int i2 = -1; float m2 = -3.4e38f;
#pragma unroll
    for (int e = 0; e < 8; ++e) if (e != i1 && logit[e] > m2) { m2 = logit[e]; i2 = e; }

    const float w2 = expf(m2 - m1);
    out[b] = (eo[i1] + w2 * eo[i2]) / (1.f + w2);
}

// ---------------------------------------------------------------------------
extern "C" void kernel_launch(void* const* d_in, const int* in_sizes, int n_in,
                              void* d_out, int out_size, void* d_ws, size_t ws_size,
                              hipStream_t stream) {
    (void)in_sizes; (void)n_in; (void)out_size;
    const float* x   = (const float*)d_in[0];
    const float* We1 = (const float*)d_in[1];
    const float* be1 = (const float*)d_in[2];
    const float* We2 = (const float*)d_in[3];
    const float* be2 = (const float*)d_in[4];
    const float* Wg1 = (const float*)d_in[5];
    const float* bg1 = (const float*)d_in[6];
    const float* Wg2 = (const float*)d_in[7];
    const float* bg2 = (const float*)d_in[8];
    float* out = (float*)d_out;

    char* ws = (char*)d_ws;
    size_t off = 0;
    float* gpart = (float*)(ws + off);                  off += (size_t)B_DIM * 128 * 4;            // 8 MB
    float* epart = (float*)(ws + off);                  off += (size_t)B_DIM * 128 * 4;            // 8 MB (esel front 1MB)
    unsigned short* panA = (unsigned short*)(ws + off); off += (size_t)B_DIM * H_DIM * 2;          // 128 MB
    unsigned short* panB = (unsigned short*)(ws + off); off += (size_t)E_DIM * H2_DIM * H_DIM * 2; // 128 MB
    const size_t NEED2 = off;
    unsigned short* panAl  = (unsigned short*)(ws + off); off += (size_t)B_DIM * H_DIM * 2;        // 128 MB
    unsigned short* panBgh = (unsigned short*)(ws + off); off += (size_t)H2_DIM * H_DIM * 2;       // 16 MB
    unsigned short* panBgl = (unsigned short*)(ws + off); off += (size_t)H2_DIM * H_DIM * 2;       // 16 MB
    int*   cnt       = (int*)(ws + off);   off += 256;
    int*   nTiles    = (int*)(ws + off);   off += 256;
    int*   tileE     = (int*)(ws + off);   off += 272 * 4;
    int*   tileB     = (int*)(ws + off);   off += 272 * 4;
    int*   sel       = (int*)(ws + off);   off += (size_t)B_DIM * 4;          // 64 KB
    float* w2f       = (float*)(ws + off); off += (size_t)B_DIM * 4;          // 64 KB
    int*   tokenlist = (int*)(ws + off);   off += (size_t)E_DIM * B_DIM * 4;  // 512 KB
    const size_t NEED1 = off;
    float* esel = epart;

    if (ws_size >= NEED1) {
        build_xA_panels_hl<<<dim3(64, 64), 256, 0, stream>>>(x, panA, panAl);
        build_wg1_panels<<<dim3(32, 64), 256, 0, stream>>>(Wg1, panBgh, panBgl);
        route_zero<<<1, 64, 0, stream>>>(cnt);
        moe_gate_panel<<<dim3(16, 128), 256, 0, stream>>>(panA, panAl, panBgh, panBgl,
                                                          bg1, Wg2, gpart);
        moe_logits_topk<<<64, 256, 0, stream>>>(gpart, bg2, sel, w2f, cnt, tokenlist);
        build_w1B_panels<<<dim3(32, 64, 8), 256, 0, stream>>>(We1, panB);  // panB L3-hot
        moe_tiletab<<<1, 64, 0, stream>>>(cnt, tileE, tileB, nTiles);
        moe_expert_sparse<<<dim3(8, 264), 512, 0, stream>>>(
            panA, panB, be1, We2, tileE, tileB, nTiles, cnt, tokenlist, esel);
        moe_finalize_sparse<<<64, 256, 0, stream>>>(esel, sel, w2f, be2, out);
    } else if (ws_size >= NEED2) {
        build_xA_panels<<<dim3(64, 64), 256, 0, stream>>>(x, panA);
        build_w1B_panels<<<dim3(32, 64, 8), 256, 0, stream>>>(We1, panB);
        moe_expert_gemm_128<<<8192, 512, 0, stream>>>(panA, panB, be1, We2, epart);
        moe_gate_gemm<<<dim3(16, 128), 256, 0, stream>>>(x, Wg1, bg1, Wg2, gpart);
        moe_finalize<8><<<64, 256, 0, stream>>>(gpart, epart, bg2, be2, out);
    } else {
        moe_expert_gemm<<<dim3(128, 128), 256, 0, stream>>>(x, We1, be1, We2, epart);
        moe_gate_gemm<<<dim3(16, 128), 256, 0, stream>>>(x, Wg1, bg1, Wg2, gpart);
        moe_finalize<16><<<64, 256, 0, stream>>>(gpart, epart, bg2, be2, out);
    }
}